// Round 10
// baseline (2967.112 us; speedup 1.0000x reference)
//
#include <hip/hip_runtime.h>
#include <hip/hip_bf16.h>
#include <math.h>

#define T_ 16
#define S_ 262
#define D_ 1024
#define H_ 16
#define HD_ 64
#define DH_ 4096
#define NTOK (T_*S_)     // 4192
#define LTOK_ 256
#define INDIM_ 768

typedef __attribute__((ext_vector_type(4))) float f32x4;
typedef __attribute__((ext_vector_type(8))) short s16x8;
typedef __attribute__((ext_vector_type(4))) short s16x4;

__device__ __forceinline__ short f2bf(float f) {
  union { float f; unsigned u; } v; v.f = f;
  unsigned r = v.u + 0x7fffu + ((v.u >> 16) & 1u);
  return (short)(r >> 16);
}
__device__ __forceinline__ float bf2f(short h) {
  union { unsigned u; float f; } v; v.u = ((unsigned)(unsigned short)h) << 16;
  return v.f;
}
__device__ __forceinline__ float softcap(float x) {
  float z = __expf(x * (2.0f / 50.0f));
  return 50.0f * (z - 1.0f) / (z + 1.0f);
}
__device__ __forceinline__ void gload16(const void* g, void* l) {
  __builtin_amdgcn_global_load_lds((const __attribute__((address_space(1))) void*)g,
                                   (__attribute__((address_space(3))) void*)l, 16, 0, 0);
}

// ---------------------------------------------------------------- GEMM
// C[M,N] = A_bf16[M,K] * W[N,K]^T
// SMALL: 0 -> 128x128 tile; 1 -> 64x64 tile.
//   TILE-SIZE LESSON (R5-R8 A/B): skinny GEMMs (N<=1024) MUST use 64² (occupancy:
//   128² -> 264 blocks = 1/CU, latency-exposed, ~600us loss). Big GEMMs use 128².
//   XCD swizzle: neutral (R7). 256² coarse 2-phase: slightly negative (R9).
// BKT: K-step 64 or 128. BK=128 only for WB=1 SMALL=1 (32KB LDS keeps ~5 blocks/CU;
//   halves barrier-drain count per FLOP for barrier-bound skinny shapes).
// OUT: 0 f32, 1 bf16, 2 fused-swiglu bf16 (out cols N/2)   RESID: 1 -> f32 +=
// PREP: 1 spatial qk rms+rope, 2 temporal (only with SMALL=0)
// ROWMAP: out row -> (row>>8)*S_+6+(row&255)
template<int SMALL, int BKT, int RESID, int BIAS, int OUT, int WB, int PERM, int PREP, int ROWMAP>
__global__ __launch_bounds__(256)
void gemm2(const short* __restrict__ A, const void* __restrict__ Wv,
           const float* __restrict__ bias, void* __restrict__ Cv,
           int M, int N, int K,
           const float* __restrict__ qg, const float* __restrict__ kg,
           const float* __restrict__ ctab, const float* __restrict__ stab)
{
  constexpr int BM    = SMALL ? 64 : 128;
  constexpr int MI    = SMALL ? 2 : 4;      // 16x16 frags per wave per dim
  constexpr int WR    = SMALL ? 32 : 64;    // per-wave tile
  constexpr int SLOTS = BKT / 8;            // 16B slots per row (8 or 16)
  constexpr int RPI   = 64 / SLOTS;         // rows per wave gload issue (8 or 4)
  constexpr int NISS  = BM / (4 * RPI);     // gload issues per wave
  constexpr int NKH   = BKT / 32;           // mfma K-halves per K-step
  __shared__ __align__(16) short As[BM*BKT];
  __shared__ __align__(16) short Bs[BM*BKT];
  const int tid = threadIdx.x;
  const int m0 = blockIdx.y * BM, n0 = blockIdx.x * BM;
  const int lane = tid & 63, wid = tid >> 6;
  const int wr = (wid >> 1) * WR, wc = (wid & 1) * WR;
  const int lr = lane & 15, lk = (lane >> 4) * 8;
  const short* Wb = (const short*)Wv;
  const float* Wf = (const float*)Wv;

  const f32x4 fzero = {0.f, 0.f, 0.f, 0.f};
  f32x4 acc[MI][MI];
  #pragma unroll
  for (int i = 0; i < MI; ++i)
    #pragma unroll
    for (int j = 0; j < MI; ++j) acc[i][j] = fzero;

  for (int k0 = 0; k0 < K; k0 += BKT) {
    // stage A (and B if WB): swizzled global source, linear LDS dest.
    // lane l -> row = base + l/SLOTS, slot = l%SLOTS; LDS off == l*16B (verified).
    #pragma unroll
    for (int i = 0; i < NISS; ++i) {
      int row = wid*(NISS*RPI) + i*RPI + (lane / SLOTS);
      int slot = lane % SLOTS;
      int gm = m0 + row; if (gm >= M) gm = M - 1;
      int gc = ((slot ^ (row & 7)) << 3);
      gload16(A + (size_t)gm*K + k0 + gc, &As[(wid*(NISS*RPI) + i*RPI)*BKT]);
    }
    if constexpr (WB) {
      #pragma unroll
      for (int i = 0; i < NISS; ++i) {
        int row = wid*(NISS*RPI) + i*RPI + (lane / SLOTS);
        int slot = lane % SLOTS;
        int gc = ((slot ^ (row & 7)) << 3);
        gload16(Wb + (size_t)(n0 + row)*K + k0 + gc, &Bs[(wid*(NISS*RPI) + i*RPI)*BKT]);
      }
    } else {
      static_assert(!(( !WB ) && BKT != 64), "fallback path requires BKT==64");
      #pragma unroll
      for (int i = 0; i < BM*8/256; ++i) {   // reg-stage f32 -> bf16 (BKT==64)
        int slot = tid + 256*i;
        int row = slot >> 3, c8 = (slot & 7) << 3;
        int gr = n0 + row;
        if (PERM) { int c = gr >> 5, q = gr & 31; gr = (q < 16) ? c*16 + q : DH_ + c*16 + (q - 16); }
        const float* wp = Wf + (size_t)gr*K + k0 + c8;
        float4 w0 = *(const float4*)wp, w1 = *(const float4*)(wp + 4);
        s16x8 b;
        b[0]=f2bf(w0.x); b[1]=f2bf(w0.y); b[2]=f2bf(w0.z); b[3]=f2bf(w0.w);
        b[4]=f2bf(w1.x); b[5]=f2bf(w1.y); b[6]=f2bf(w1.z); b[7]=f2bf(w1.w);
        *(s16x8*)&Bs[row*BKT + (c8 ^ ((row & 7) << 3))] = b;
      }
    }
    __syncthreads();
    #pragma unroll
    for (int kh = 0; kh < NKH; ++kh) {
      const int col0 = kh*32 + lk;
      s16x8 af[MI], bfr[MI];
      #pragma unroll
      for (int mi = 0; mi < MI; ++mi) {
        int row = wr + mi*16 + lr;
        af[mi] = *(const s16x8*)&As[row*BKT + (col0 ^ ((row & 7) << 3))];
      }
      #pragma unroll
      for (int ni = 0; ni < MI; ++ni) {
        int row = wc + ni*16 + lr;
        bfr[ni] = *(const s16x8*)&Bs[row*BKT + (col0 ^ ((row & 7) << 3))];
      }
      #pragma unroll
      for (int mi = 0; mi < MI; ++mi)
        #pragma unroll
        for (int ni = 0; ni < MI; ++ni)
          acc[mi][ni] = __builtin_amdgcn_mfma_f32_16x16x32_bf16(af[mi], bfr[ni], acc[mi][ni], 0, 0, 0);
    }
    __syncthreads();
  }
  const int gg = (lane >> 4) * 4;
  if constexpr (OUT == 2) {
    #pragma unroll
    for (int mi = 0; mi < MI; ++mi)
      #pragma unroll
      for (int np = 0; np < MI/2; ++np) {
        const int ni = np*2;
        const int ocol = ((n0 + wc + ni*16) >> 5) * 16 + lr;
        #pragma unroll
        for (int r = 0; r < 4; ++r) {
          int row = m0 + wr + mi*16 + gg + r;
          if (row < M) {
            float g = acc[mi][ni][r], v = acc[mi][ni+1][r];
            float sl = g / (1.f + __expf(-g));
            ((short*)Cv)[(size_t)row * (N >> 1) + ocol] = f2bf(sl * v);
          }
        }
      }
  } else if constexpr (PREP != 0) {
    const int colsec = n0 + wc;
    const bool isv = (colsec >= 2048);
    const float* gp = (colsec < 1024) ? qg : kg;
    float gv[MI];
    if (!isv) {
      #pragma unroll
      for (int ni = 0; ni < MI; ++ni) gv[ni] = gp[ni*16 + lr];
    }
    #pragma unroll
    for (int mi = 0; mi < MI; ++mi) {
      #pragma unroll
      for (int r = 0; r < 4; ++r) {
        int row = m0 + wr + mi*16 + gg + r;
        int rowc = row < M ? row : M - 1;
        float vv[MI];
        #pragma unroll
        for (int ni = 0; ni < MI; ++ni) vv[ni] = acc[mi][ni][r];
        if (!isv) {
          float ss = vv[0]*vv[0] + vv[1]*vv[1] + vv[2]*vv[2] + vv[3]*vv[3];
          ss += __shfl_xor(ss, 1);
          ss += __shfl_xor(ss, 2);
          ss += __shfl_xor(ss, 4);
          ss += __shfl_xor(ss, 8);
          float sc = rsqrtf(ss * (1.f/64.f) + 1e-6f);
          int pos = (PREP == 1) ? (rowc % S_) : (rowc / S_);
          float c0 = ctab[pos*32 + lr],      s0 = stab[pos*32 + lr];
          float c1 = ctab[pos*32 + 16 + lr], s1 = stab[pos*32 + 16 + lr];
          float a0 = vv[0]*sc*gv[0], a1 = vv[1]*sc*gv[1];
          float a2 = vv[2]*sc*gv[2], a3 = vv[3]*sc*gv[3];
          vv[0] = a0*c0 - a2*s0;
          vv[1] = a1*c1 - a3*s1;
          vv[2] = a0*s0 + a2*c0;
          vv[3] = a1*s1 + a3*c1;
        }
        if (row < M) {
          #pragma unroll
          for (int ni = 0; ni < MI; ++ni)
            ((short*)Cv)[(size_t)row * N + n0 + wc + ni*16 + lr] = f2bf(vv[ni]);
        }
      }
    }
  } else {
    #pragma unroll
    for (int mi = 0; mi < MI; ++mi)
      #pragma unroll
      for (int ni = 0; ni < MI; ++ni) {
        int col = n0 + wc + ni*16 + lr;
        #pragma unroll
        for (int r = 0; r < 4; ++r) {
          int row = m0 + wr + mi*16 + gg + r;
          if (row < M) {
            float v = acc[mi][ni][r];
            if (BIAS) v += bias[col];
            size_t orow = ROWMAP ? (size_t)((row >> 8) * S_ + 6 + (row & 255)) : (size_t)row;
            size_t idx = orow * N + col;
            if (RESID == 1)       ((float*)Cv)[idx] += v;
            else if (OUT == 1)    ((short*)Cv)[idx]  = f2bf(v);
            else                  ((float*)Cv)[idx]  = v;
          }
        }
      }
  }
}

// ---------------------------------------------------------------- RMSNorm (wave per row)
template<int FINAL>
__global__ __launch_bounds__(256)
void rmsnorm_k(const float* __restrict__ x, const float* __restrict__ w, short* __restrict__ h)
{
  const int lane = threadIdx.x & 63;
  const int row = blockIdx.x*4 + (threadIdx.x >> 6);
  const int xrow = FINAL ? ((row >> 8) * S_ + 6 + (row & 255)) : row;
  const float* xp = x + (size_t)xrow*D_;
  float4 v[4];
  #pragma unroll
  for (int j = 0; j < 4; ++j) v[j] = *(const float4*)(xp + j*256 + lane*4);
  float ss = 0.f;
  #pragma unroll
  for (int j = 0; j < 4; ++j) ss += v[j].x*v[j].x + v[j].y*v[j].y + v[j].z*v[j].z + v[j].w*v[j].w;
  #pragma unroll
  for (int m = 1; m < 64; m <<= 1) ss += __shfl_xor(ss, m);
  const float sc = rsqrtf(ss * (1.f/1024.f) + 1e-6f);
  #pragma unroll
  for (int j = 0; j < 4; ++j) {
    float4 wv = *(const float4*)(w + j*256 + lane*4);
    s16x4 hv;
    hv[0] = f2bf(v[j].x*sc*wv.x); hv[1] = f2bf(v[j].y*sc*wv.y);
    hv[2] = f2bf(v[j].z*sc*wv.z); hv[3] = f2bf(v[j].w*sc*wv.w);
    *(s16x4*)(h + (size_t)row*D_ + j*256 + lane*4) = hv;
  }
}

// ---------------------------------------------------------------- rope tables
__global__ void rope_tab_k(float* __restrict__ ct, float* __restrict__ st, int npos)
{
  int i = blockIdx.x*256 + threadIdx.x;
  if (i >= npos*32) return;
  int pos = i >> 5, fi = i & 31;
  float ang = (float)pos * expf((float)fi * (-9.210340371976184f/32.f));
  float s, c; sincosf(ang, &s, &c);
  ct[i] = c; st[i] = s;
}

// ---------------------------------------------------------------- spatial attention
__global__ __launch_bounds__(256)
void attn_spatial_k(const short* __restrict__ qkv, short* __restrict__ o)
{
  __shared__ __align__(16) short Vt[64][296];
  __shared__ __align__(16) short Pl[4][16][296];
  const int tid = threadIdx.x;
  const int b = blockIdx.x;          // T*H = 256
  const int t = b >> 4, h = b & 15;
  const short* kbase = qkv + (size_t)t*S_*3072 + 1024 + h*64;
  const short* vbase = kbase + 1024;
  const s16x8 zv = {0,0,0,0,0,0,0,0};
  #pragma unroll
  for (int i = 0; i < 9; ++i) {
    int slot = tid + 256*i;
    if (slot < 2176) {
      int row = slot >> 3, c8 = (slot & 7) * 8;
      s16x8 v = zv;
      if (row < S_) v = *(const s16x8*)(vbase + (size_t)row*3072 + c8);
      #pragma unroll
      for (int j = 0; j < 8; ++j) Vt[c8 + j][row] = v[j];
    }
  }
  #pragma unroll
  for (int i = 0; i < 6; ++i) {
    int slot = tid + 256*i;
    Vt[slot / 24][272 + (slot % 24)] = 0;
  }
  if (tid < 64) o[(size_t)t*S_*D_ + h*64 + tid] = vbase[tid];
  __syncthreads();

  const int lane = tid & 63, wid = tid >> 6;
  const int lr = lane & 15, lk = (lane >> 4) * 8;
  const int gg = (lane >> 4) * 4;
  const f32x4 fzero = {0.f,0.f,0.f,0.f};

  for (int qt = wid; qt < 17; qt += 4) {
    int qrow = qt*16 + lr; if (qrow >= S_) qrow = 0;
    const short* qbase = qkv + (size_t)(t*S_ + qrow)*3072 + h*64;
    s16x8 qf0 = *(const s16x8*)(qbase + lk);
    s16x8 qf1 = *(const s16x8*)(qbase + 32 + lk);

    f32x4 lg[17];
    #pragma unroll
    for (int nt = 0; nt < 17; ++nt) lg[nt] = fzero;
    __builtin_amdgcn_s_setprio(1);
    #pragma unroll
    for (int nt = 0; nt < 17; ++nt) {
      int krow = nt*16 + lr; if (krow >= S_) krow = S_ - 1;
      s16x8 kf0 = *(const s16x8*)(kbase + (size_t)krow*3072 + lk);
      s16x8 kf1 = *(const s16x8*)(kbase + (size_t)krow*3072 + 32 + lk);
      lg[nt] = __builtin_amdgcn_mfma_f32_16x16x32_bf16(qf0, kf0, lg[nt], 0, 0, 0);
      lg[nt] = __builtin_amdgcn_mfma_f32_16x16x32_bf16(qf1, kf1, lg[nt], 0, 0, 0);
    }
    __builtin_amdgcn_s_setprio(0);
    #pragma unroll
    for (int r = 0; r < 4; ++r) {
      float mx = -1e30f;
      #pragma unroll
      for (int nt = 0; nt < 17; ++nt) {
        float v = softcap(lg[nt][r] * 0.125f);
        if (nt*16 + lr >= S_) v = -1e30f;
        lg[nt][r] = v;
        mx = fmaxf(mx, v);
      }
      mx = fmaxf(mx, __shfl_xor(mx, 1));
      mx = fmaxf(mx, __shfl_xor(mx, 2));
      mx = fmaxf(mx, __shfl_xor(mx, 4));
      mx = fmaxf(mx, __shfl_xor(mx, 8));
      float sum = 0.f;
      #pragma unroll
      for (int nt = 0; nt < 17; ++nt) { float pe = __expf(lg[nt][r] - mx); lg[nt][r] = pe; sum += pe; }
      sum += __shfl_xor(sum, 1);
      sum += __shfl_xor(sum, 2);
      sum += __shfl_xor(sum, 4);
      sum += __shfl_xor(sum, 8);
      float is = 1.f / sum;
      #pragma unroll
      for (int nt = 0; nt < 17; ++nt) Pl[wid][gg + r][nt*16 + lr] = f2bf(lg[nt][r] * is);
      Pl[wid][gg + r][272 + lr] = 0;
    }
    f32x4 oacc[4];
    #pragma unroll
    for (int ni = 0; ni < 4; ++ni) oacc[ni] = fzero;
    __builtin_amdgcn_s_setprio(1);
    #pragma unroll
    for (int ks = 0; ks < 9; ++ks) {
      s16x8 pf = *(const s16x8*)&Pl[wid][lr][ks*32 + lk];
      #pragma unroll
      for (int ni = 0; ni < 4; ++ni) {
        s16x8 vf = *(const s16x8*)&Vt[ni*16 + lr][ks*32 + lk];
        oacc[ni] = __builtin_amdgcn_mfma_f32_16x16x32_bf16(pf, vf, oacc[ni], 0, 0, 0);
      }
    }
    __builtin_amdgcn_s_setprio(0);
    #pragma unroll
    for (int ni = 0; ni < 4; ++ni)
      #pragma unroll
      for (int r = 0; r < 4; ++r) {
        int q = qt*16 + gg + r;
        if (q < S_ && q != 0) o[(size_t)(t*S_ + q)*D_ + h*64 + ni*16 + lr] = f2bf(oacc[ni][r]);
      }
  }
}

// ---------------------------------------------------------------- temporal attention
__global__ __launch_bounds__(256)
void attn_temporal_k(const short* __restrict__ qkv, short* __restrict__ o)
{
  __shared__ float Ql[4][16][68];
  __shared__ float Kl[4][16][68];
  __shared__ float Vl[4][16][68];
  __shared__ float Pl2[4][16][17];
  const int tid = threadIdx.x, lane = tid & 63, wid = tid >> 6;
  const int gw = blockIdx.x*4 + wid;
  const int s = gw >> 4, h = gw & 15;
  const int tt = lane >> 2, dp = (lane & 3) * 16;
  const short* base = qkv + (size_t)(tt*S_ + s)*3072 + h*64 + dp;
  #pragma unroll
  for (int part = 0; part < 3; ++part) {
    const short* bp = base + part*1024;
    s16x8 v0 = *(const s16x8*)(bp);
    s16x8 v1 = *(const s16x8*)(bp + 8);
    float* dst = (part == 0) ? &Ql[wid][tt][dp] : (part == 1) ? &Kl[wid][tt][dp] : &Vl[wid][tt][dp];
    #pragma unroll
    for (int j = 0; j < 8; ++j) { dst[j] = bf2f(v0[j]); dst[8 + j] = bf2f(v1[j]); }
  }
  __syncthreads();
  const int qr = lane >> 2;
  float qv[64];
  #pragma unroll
  for (int j = 0; j < 64; ++j) qv[j] = Ql[wid][qr][j];
  float pvals[4];
  #pragma unroll
  for (int i = 0; i < 4; ++i) {
    int kt = (lane & 3) + i*4;
    float d = 0.f;
    #pragma unroll
    for (int j = 0; j < 64; ++j) d += qv[j] * Kl[wid][kt][j];
    d *= 0.125f;
    d = softcap(d);
    bool keep = (kt <= qr) && (kt + 9 >= qr);
    pvals[i] = keep ? d : -1e30f;
  }
  float mx = fmaxf(fmaxf(pvals[0], pvals[1]), fmaxf(pvals[2], pvals[3]));
  mx = fmaxf(mx, __shfl_xor(mx, 1));
  mx = fmaxf(mx, __shfl_xor(mx, 2));
  float sum = 0.f;
  #pragma unroll
  for (int i = 0; i < 4; ++i) { pvals[i] = __expf(pvals[i] - mx); sum += pvals[i]; }
  sum += __shfl_xor(sum, 1);
  sum += __shfl_xor(sum, 2);
  float is = 1.f / sum;
  #pragma unroll
  for (int i = 0; i < 4; ++i) Pl2[wid][qr][(lane & 3) + i*4] = pvals[i] * is;
  __syncthreads();
  float acc[16];
  #pragma unroll
  for (int j = 0; j < 16; ++j) acc[j] = 0.f;
  #pragma unroll
  for (int kt = 0; kt < 16; ++kt) {
    float pv = Pl2[wid][qr][kt];
    #pragma unroll
    for (int j = 0; j < 16; ++j) acc[j] += pv * Vl[wid][kt][dp + j];
  }
  short* op = o + (size_t)(qr*S_ + s)*D_ + h*64 + dp;
  #pragma unroll
  for (int j = 0; j < 16; ++j) op[j] = f2bf(acc[j]);
}

// ---------------------------------------------------------------- conversions / prologue
struct CvtJobs {
  const float* src[10];
  short* dst[10];
  int end[10];
  int njobs;
};

__global__ void cvt_multi_k(CvtJobs jobs)
{
  int q = blockIdx.x*256 + threadIdx.x;
  int j = 0;
  while (j < jobs.njobs && q >= jobs.end[j]) ++j;
  if (j >= jobs.njobs) return;
  int base = (j == 0) ? 0 : jobs.end[j-1];
  size_t idx = (size_t)(q - base);
  float4 v = *(const float4*)(jobs.src[j] + idx*4);
  s16x4 ov; ov[0]=f2bf(v.x); ov[1]=f2bf(v.y); ov[2]=f2bf(v.z); ov[3]=f2bf(v.w);
  *(s16x4*)(jobs.dst[j] + idx*4) = ov;
}

__global__ void cvt_f32_bf16_k(const float* __restrict__ in, short* __restrict__ out, int n4)
{
  int i = blockIdx.x*256 + threadIdx.x;
  if (i >= n4) return;
  float4 v = *(const float4*)(in + (size_t)i*4);
  s16x4 ov; ov[0]=f2bf(v.x); ov[1]=f2bf(v.y); ov[2]=f2bf(v.z); ov[3]=f2bf(v.w);
  *(s16x4*)(out + (size_t)i*4) = ov;
}

__global__ void cvt_w12_k(const float* __restrict__ in, short* __restrict__ out)
{
  int pb = blockIdx.x;             // 8 layers * 8192 rows
  int l = pb >> 13, pr = pb & 8191;
  int c = pr >> 5, q = pr & 31;
  int orig = (q < 16) ? c*16 + q : DH_ + c*16 + (q - 16);
  const float* ip = in + ((size_t)l*8192 + orig)*1024 + threadIdx.x*4;
  short* op = out + ((size_t)l*8192 + pr)*1024 + threadIdx.x*4;
  float4 v = *(const float4*)ip;
  s16x4 ov; ov[0]=f2bf(v.x); ov[1]=f2bf(v.y); ov[2]=f2bf(v.z); ov[3]=f2bf(v.w);
  *(s16x4*)op = ov;
}

__global__ void timestep_embed_k(const float* __restrict__ sig, float* __restrict__ emb)
{
  int tid = threadIdx.x;
  int n = tid >> 4;
  int j0 = (tid & 15) * 16;
  float tv = sig[n];
  for (int j = j0; j < j0 + 16; ++j) {
    int half = j & 127;
    float freq = expf(-9.210340371976184f * (float)half / 128.f);
    float a = tv * freq;
    emb[n*256 + j] = (j < 128) ? cosf(a) : sinf(a);
  }
}

__global__ void noise_mlp1_k(const float* __restrict__ emb, const float* __restrict__ w1,
                             const float* __restrict__ b1, float* __restrict__ hid)
{
  const int o = blockIdx.x*256 + threadIdx.x;
  const int n = o >> 10, e = o & 1023;
  const float4* er = (const float4*)(emb + n*256);
  const float4* wr = (const float4*)(w1 + (size_t)e*256);
  float s = b1[e];
  for (int k = 0; k < 64; ++k) { float4 a = er[k]; float4 b = wr[k]; s += a.x*b.x + a.y*b.y + a.z*b.z + a.w*b.w; }
  hid[o] = s / (1.f + __expf(-s));
}

__global__ void noise_mlp2_k(const float* __restrict__ hid, const float* __restrict__ w2,
                             const float* __restrict__ b2, float* __restrict__ sg)
{
  const int o = blockIdx.x*256 + threadIdx.x;
  const int n = o >> 10, e = o & 1023;
  const float4* hr = (const float4*)(hid + n*1024);
  const float4* wr = (const float4*)(w2 + (size_t)e*1024);
  float s = b2[e];
  for (int k = 0; k < 256; ++k) { float4 a = hr[k]; float4 b = wr[k]; s += a.x*b.x + a.y*b.y + a.z*b.z + a.w*b.w; }
  sg[o] = s;
}

__global__ void act_embed_k(const float* __restrict__ actions, const float* __restrict__ base,
                            const float* __restrict__ apw, const float* __restrict__ apb,
                            float* __restrict__ ar)
{
  const int o = blockIdx.x*256 + threadIdx.x;
  const int n = o >> 10, e = o & 1023;
  float s = base[e] + apb[e];
  #pragma unroll
  for (int j = 0; j < 8; ++j) s += actions[n*8 + j] * apw[(size_t)e*8 + j];
  ar[o] = s;
}

__global__ void fill6_k(const float* __restrict__ sig, const float* __restrict__ act,
                        const float* __restrict__ reg, float* __restrict__ x)
{
  const int b = blockIdx.x;            // 16*6
  const int t = b / 6, s = b % 6;
  const int d = threadIdx.x * 4;
  float4 v;
  if (s == 0)      v = *(const float4*)(sig + t*D_ + d);
  else if (s == 1) v = *(const float4*)(act + t*D_ + d);
  else             v = *(const float4*)(reg + (s-2)*D_ + d);
  *(float4*)(x + (size_t)(t*S_ + s)*D_ + d) = v;
}

// ---------------------------------------------------------------- host
extern "C" void kernel_launch(void* const* d_in, const int* in_sizes, int n_in,
                              void* d_out, int out_size, void* d_ws, size_t ws_size,
                              hipStream_t stream)
{
  (void)in_sizes; (void)n_in; (void)out_size;
  const float* noisy   = (const float*)d_in[0];
  const float* sig_lv  = (const float*)d_in[1];
  const float* actions = (const float*)d_in[2];
  const float* in_proj = (const float*)d_in[3];
  const float* nw1     = (const float*)d_in[4];
  const float* nb1     = (const float*)d_in[5];
  const float* nw2     = (const float*)d_in[6];
  const float* nb2     = (const float*)d_in[7];
  const float* base_ae = (const float*)d_in[8];
  const float* apw     = (const float*)d_in[9];
  const float* apb     = (const float*)d_in[10];
  const float* regtok  = (const float*)d_in[11];
  const float* ln1w    = (const float*)d_in[12];
  const float* s_wqkv  = (const float*)d_in[13];
  const float* s_wo    = (const float*)d_in[14];
  const float* s_qg    = (const float*)d_in[15];
  const float* s_kg    = (const float*)d_in[16];
  const float* lntw    = (const float*)d_in[17];
  const float* t_wqkv  = (const float*)d_in[18];
  const float* t_wo    = (const float*)d_in[19];
  const float* t_qg    = (const float*)d_in[20];
  const float* t_kg    = (const float*)d_in[21];
  const float* ln2w    = (const float*)d_in[22];
  const float* w12     = (const float*)d_in[23];
  const float* w3      = (const float*)d_in[24];
  const float* fnw     = (const float*)d_in[25];
  const float* outw    = (const float*)d_in[26];
  const float* outb    = (const float*)d_in[27];

  char* p = (char*)d_ws;
  auto take = [&](size_t n) { char* r = p; p += n; return r; };
  float* x   = (float*)take((size_t)NTOK*D_*4);
  short* hb  = (short*)take((size_t)NTOK*D_*2);
  short* qkv = (short*)take((size_t)NTOK*3072*2);
  short* ob  = (short*)take((size_t)NTOK*D_*2);
  short* mb  = qkv;                               // spans qkv+ob exactly (NTOK*4096*2)
  short* nlb = (short*)take((size_t)4096*INDIM_*2);
  float* emb = (float*)take(16*256*4);
  float* hid = (float*)take(16*1024*4);
  float* sgb = (float*)take(16*1024*4);
  float* acr = (float*)take(16*1024*4);
  float* csS = (float*)take(S_*32*4);
  float* snS = (float*)take(S_*32*4);
  float* csT = (float*)take(16*32*4);
  float* snT = (float*)take(16*32*4);
  short* wqkv_s_bf = (short*)take((size_t)8*3*D_*D_*2);
  short* wo_s_bf   = (short*)take((size_t)8*D_*D_*2);
  short* wqkv_t_bf = (short*)take((size_t)2*3*D_*D_*2);
  short* wo_t_bf   = (short*)take((size_t)2*D_*D_*2);
  short* w12_bf    = (short*)take((size_t)8*2*DH_*D_*2);
  short* w3_bf     = (short*)take((size_t)8*D_*DH_*2);
  short* inp_bf    = (short*)take((size_t)D_*INDIM_*2);
  short* outw_bf   = (short*)take((size_t)INDIM_*D_*2);
  const size_t full_need = (size_t)(p - (char*)d_ws);
  const bool wb = ws_size >= full_need;

  if (wb) {
    CvtJobs jobs;
    int acc_q = 0, nj = 0;
    auto add = [&](const float* s, short* d, size_t elems) {
      jobs.src[nj] = s; jobs.dst[nj] = d;
      acc_q += (int)(elems / 4); jobs.end[nj] = acc_q; ++nj;
    };
    add(s_wqkv, wqkv_s_bf, (size_t)8*3*D_*D_);
    add(s_wo,   wo_s_bf,   (size_t)8*D_*D_);
    add(t_wqkv,                     wqkv_t_bf,                   (size_t)3*D_*D_);
    add(t_wqkv + (size_t)4*3*D_*D_, wqkv_t_bf + (size_t)3*D_*D_, (size_t)3*D_*D_);
    add(t_wo,                       wo_t_bf,                     (size_t)D_*D_);
    add(t_wo + (size_t)4*D_*D_,     wo_t_bf + (size_t)D_*D_,     (size_t)D_*D_);
    add(w3,   w3_bf,   (size_t)8*D_*DH_);
    add(in_proj, inp_bf, (size_t)D_*INDIM_);
    add(outw,    outw_bf,(size_t)INDIM_*D_);
    add(noisy,   nlb,    (size_t)4096*INDIM_);
    jobs.njobs = nj;
    cvt_multi_k<<<(acc_q + 255)/256, 256, 0, stream>>>(jobs);
    cvt_w12_k<<<65536, 256, 0, stream>>>(w12, w12_bf);
  } else {
    cvt_f32_bf16_k<<<3072, 256, 0, stream>>>(noisy, nlb, 4096*INDIM_/4);
  }
  rope_tab_k<<<33, 256, 0, stream>>>(csS, snS, S_);
  rope_tab_k<<<2,  256, 0, stream>>>(csT, snT, 16);

  // prologue
  timestep_embed_k<<<1, 256, 0, stream>>>(sig_lv, emb);
  noise_mlp1_k<<<64, 256, 0, stream>>>(emb, nw1, nb1, hid);
  noise_mlp2_k<<<64, 256, 0, stream>>>(hid, nw2, nb2, sgb);
  act_embed_k<<<64, 256, 0, stream>>>(actions, base_ae, apw, apb, acr);
  if (wb) gemm2<1,128,0,0,0,1,0,0,1><<<dim3(16,64), 256, 0, stream>>>(nlb, inp_bf,  nullptr, x, 4096, D_, INDIM_, nullptr, nullptr, nullptr, nullptr);
  else    gemm2<1,64,0,0,0,0,0,0,1><<<dim3(16,64), 256, 0, stream>>>(nlb, in_proj, nullptr, x, 4096, D_, INDIM_, nullptr, nullptr, nullptr, nullptr);
  fill6_k<<<96, 256, 0, stream>>>(sgb, acr, regtok, x);

  for (int l = 0; l < 8; ++l) {
    rmsnorm_k<0><<<NTOK/4, 256, 0, stream>>>(x, ln1w + l*D_, hb);
    if (wb) gemm2<0,64,0,0,1,1,0,1,0><<<dim3(24,33), 256, 0, stream>>>(hb, wqkv_s_bf + (size_t)l*3*D_*D_, nullptr, qkv, NTOK, 3*D_, D_, s_qg + l*HD_, s_kg + l*HD_, csS, snS);
    else    gemm2<0,64,0,0,1,0,0,1,0><<<dim3(24,33), 256, 0, stream>>>(hb, s_wqkv   + (size_t)l*3*D_*D_, nullptr, qkv, NTOK, 3*D_, D_, s_qg + l*HD_, s_kg + l*HD_, csS, snS);
    attn_spatial_k<<<256, 256, 0, stream>>>(qkv, ob);
    if (wb) gemm2<1,128,1,0,0,1,0,0,0><<<dim3(16,66), 256, 0, stream>>>(ob, wo_s_bf + (size_t)l*D_*D_, nullptr, x, NTOK, D_, D_, nullptr, nullptr, nullptr, nullptr);
    else    gemm2<1,64,1,0,0,0,0,0,0><<<dim3(16,66), 256, 0, stream>>>(ob, s_wo    + (size_t)l*D_*D_, nullptr, x, NTOK, D_, D_, nullptr, nullptr, nullptr, nullptr);
    if (l % 4 == 0) {
      const int ls = l / 4;
      rmsnorm_k<0><<<NTOK/4, 256, 0, stream>>>(x, lntw + l*D_, hb);
      if (wb) gemm2<0,64,0,0,1,1,0,2,0><<<dim3(24,33), 256, 0, stream>>>(hb, wqkv_t_bf + (size_t)ls*3*D_*D_, nullptr, qkv, NTOK, 3*D_, D_, t_qg + l*HD_, t_kg + l*HD_, csT, snT);
      else    gemm2<0,64,0,0,1,0,0,2,0><<<dim3(24,33), 256, 0, stream>>>(hb, t_wqkv    + (size_t)l*3*D_*D_,  nullptr, qkv, NTOK, 3*D_, D_, t_qg + l*HD_, t_kg + l*HD_, csT, snT);
      attn_temporal_k<<<1048, 256, 0, stream>>>(qkv, ob);
      if (wb) gemm2<1,128,1,0,0,1,0,0,0><<<dim3(16,66), 256, 0, stream>>>(ob, wo_t_bf + (size_t)ls*D_*D_, nullptr, x, NTOK, D_, D_, nullptr, nullptr, nullptr, nullptr);
      else    gemm2<1,64,1,0,0,0,0,0,0><<<dim3(16,66), 256, 0, stream>>>(ob, t_wo    + (size_t)l*D_*D_,  nullptr, x, NTOK, D_, D_, nullptr, nullptr, nullptr, nullptr);
    }
    rmsnorm_k<0><<<NTOK/4, 256, 0, stream>>>(x, ln2w + l*D_, hb);
    if (wb) gemm2<0,64,0,0,2,1,0,0,0><<<dim3(64,33), 256, 0, stream>>>(hb, w12_bf + (size_t)l*2*DH_*D_, nullptr, mb, NTOK, 2*DH_, D_, nullptr, nullptr, nullptr, nullptr);
    else    gemm2<0,64,0,0,2,0,1,0,0><<<dim3(64,33), 256, 0, stream>>>(hb, w12    + (size_t)l*2*DH_*D_, nullptr, mb, NTOK, 2*DH_, D_, nullptr, nullptr, nullptr, nullptr);
    if (wb) gemm2<1,128,1,0,0,1,0,0,0><<<dim3(16,66), 256, 0, stream>>>(mb, w3_bf + (size_t)l*D_*DH_, nullptr, x, NTOK, D_, DH_, nullptr, nullptr, nullptr, nullptr);
    else    gemm2<1,64,1,0,0,0,0,0,0><<<dim3(16,66), 256, 0, stream>>>(mb, w3    + (size_t)l*D_*DH_, nullptr, x, NTOK, D_, DH_, nullptr, nullptr, nullptr, nullptr);
  }
  rmsnorm_k<1><<<1024, 256, 0, stream>>>(x, fnw, hb);
  if (wb) gemm2<1,128,0,1,0,1,0,0,0><<<dim3(12,64), 256, 0, stream>>>(hb, outw_bf, outb, (float*)d_out, 4096, INDIM_, D_, nullptr, nullptr, nullptr, nullptr);
  else    gemm2<1,64,0,1,0,0,0,0,0><<<dim3(12,64), 256, 0, stream>>>(hb, outw,    outb, (float*)d_out, 4096, INDIM_, D_, nullptr, nullptr, nullptr, nullptr);
}

// Round 12
// 2814.642 us; speedup vs baseline: 1.0542x; 1.0542x over previous
//
#include <hip/hip_runtime.h>
#include <hip/hip_bf16.h>
#include <math.h>

#define T_ 16
#define S_ 262
#define D_ 1024
#define H_ 16
#define HD_ 64
#define DH_ 4096
#define NTOK (T_*S_)     // 4192
#define LTOK_ 256
#define INDIM_ 768

typedef __attribute__((ext_vector_type(4))) float f32x4;
typedef __attribute__((ext_vector_type(8))) short s16x8;
typedef __attribute__((ext_vector_type(4))) short s16x4;

__device__ __forceinline__ short f2bf(float f) {
  union { float f; unsigned u; } v; v.f = f;
  unsigned r = v.u + 0x7fffu + ((v.u >> 16) & 1u);
  return (short)(r >> 16);
}
__device__ __forceinline__ float bf2f(short h) {
  union { unsigned u; float f; } v; v.u = ((unsigned)(unsigned short)h) << 16;
  return v.f;
}
__device__ __forceinline__ float softcap(float x) {
  float z = __expf(x * (2.0f / 50.0f));
  return 50.0f * (z - 1.0f) / (z + 1.0f);
}
__device__ __forceinline__ void gload16(const void* g, void* l) {
  __builtin_amdgcn_global_load_lds((const __attribute__((address_space(1))) void*)g,
                                   (__attribute__((address_space(3))) void*)l, 16, 0, 0);
}

// ---------------------------------------------------------------- GEMM
// C[M,N] = A_bf16[M,K] * W[N,K]^T
// SMALL: 0 -> 128x128 tile; 1 -> 64x64 tile.
//   TILE-SIZE LESSON (R5/R6/R7 A/B): skinny GEMMs (N<=1024, M~4224) MUST use 64²:
//   128² gives 264 blocks = 1 block/CU = 1 wave/SIMD, fully latency-exposed
//   (~600us total loss). 64² gives ~4 blocks/CU -> inter-block overlap. Big GEMMs
//   (qkv N=3072, w12 N=8192) use 128² for MFMA density. XCD swizzle: neutral (R7).
// OUT: 0 f32, 1 bf16, 2 fused-swiglu bf16 (out cols N/2)   RESID: 1 -> f32 +=
// PREP: 1 spatial qk rms+rope, 2 temporal (only with SMALL=0)
// ROWMAP: out row -> (row>>8)*S_+6+(row&255)
template<int SMALL, int RESID, int BIAS, int OUT, int WB, int PERM, int PREP, int ROWMAP>
__global__ __launch_bounds__(256)
void gemm2(const short* __restrict__ A, const void* __restrict__ Wv,
           const float* __restrict__ bias, void* __restrict__ Cv,
           int M, int N, int K,
           const float* __restrict__ qg, const float* __restrict__ kg,
           const float* __restrict__ ctab, const float* __restrict__ stab)
{
  constexpr int BM   = SMALL ? 64 : 128;
  constexpr int MI   = SMALL ? 2 : 4;     // 16x16 frags per wave per dim
  constexpr int WR   = SMALL ? 32 : 64;   // per-wave tile
  constexpr int NSTG = SMALL ? 2 : 4;     // staging iters (8 rows/wave each)
  __shared__ __align__(16) short As[BM*64];
  __shared__ __align__(16) short Bs[BM*64];
  const int tid = threadIdx.x;
  const int m0 = blockIdx.y * BM, n0 = blockIdx.x * BM;
  const int lane = tid & 63, wid = tid >> 6;
  const int wr = (wid >> 1) * WR, wc = (wid & 1) * WR;
  const int lr = lane & 15, lk = (lane >> 4) * 8;
  const short* Wb = (const short*)Wv;
  const float* Wf = (const float*)Wv;

  const f32x4 fzero = {0.f, 0.f, 0.f, 0.f};
  f32x4 acc[MI][MI];
  #pragma unroll
  for (int i = 0; i < MI; ++i)
    #pragma unroll
    for (int j = 0; j < MI; ++j) acc[i][j] = fzero;

  for (int k0 = 0; k0 < K; k0 += 64) {
    #pragma unroll
    for (int i = 0; i < NSTG; ++i) {         // A tile, swizzled global source
      int row = wid*(NSTG*8) + i*8 + (lane >> 3);
      int gm = m0 + row; if (gm >= M) gm = M - 1;
      int gc = (((lane & 7) ^ (row & 7)) << 3);
      gload16(A + (size_t)gm*K + k0 + gc, &As[(wid*(NSTG*8) + i*8)*64]);
    }
    if constexpr (WB) {
      #pragma unroll
      for (int i = 0; i < NSTG; ++i) {
        int row = wid*(NSTG*8) + i*8 + (lane >> 3);
        int gc = (((lane & 7) ^ (row & 7)) << 3);
        gload16(Wb + (size_t)(n0 + row)*K + k0 + gc, &Bs[(wid*(NSTG*8) + i*8)*64]);
      }
    } else {
      #pragma unroll
      for (int i = 0; i < NSTG; ++i) {       // fallback: reg-stage f32 -> bf16
        int slot = tid + 256*i;
        int row = slot >> 3, c8 = (slot & 7) << 3;
        int gr = n0 + row;
        if (PERM) { int c = gr >> 5, q = gr & 31; gr = (q < 16) ? c*16 + q : DH_ + c*16 + (q - 16); }
        const float* wp = Wf + (size_t)gr*K + k0 + c8;
        float4 w0 = *(const float4*)wp, w1 = *(const float4*)(wp + 4);
        s16x8 b;
        b[0]=f2bf(w0.x); b[1]=f2bf(w0.y); b[2]=f2bf(w0.z); b[3]=f2bf(w0.w);
        b[4]=f2bf(w1.x); b[5]=f2bf(w1.y); b[6]=f2bf(w1.z); b[7]=f2bf(w1.w);
        *(s16x8*)&Bs[row*64 + (c8 ^ ((row & 7) << 3))] = b;
      }
    }
    __syncthreads();
    #pragma unroll
    for (int kh = 0; kh < 2; ++kh) {
      const int col0 = kh*32 + lk;
      s16x8 af[MI], bfr[MI];
      #pragma unroll
      for (int mi = 0; mi < MI; ++mi) {
        int row = wr + mi*16 + lr;
        af[mi] = *(const s16x8*)&As[row*64 + (col0 ^ ((row & 7) << 3))];
      }
      #pragma unroll
      for (int ni = 0; ni < MI; ++ni) {
        int row = wc + ni*16 + lr;
        bfr[ni] = *(const s16x8*)&Bs[row*64 + (col0 ^ ((row & 7) << 3))];
      }
      #pragma unroll
      for (int mi = 0; mi < MI; ++mi)
        #pragma unroll
        for (int ni = 0; ni < MI; ++ni)
          acc[mi][ni] = __builtin_amdgcn_mfma_f32_16x16x32_bf16(af[mi], bfr[ni], acc[mi][ni], 0, 0, 0);
    }
    __syncthreads();
  }
  const int gg = (lane >> 4) * 4;
  if constexpr (OUT == 2) {
    #pragma unroll
    for (int mi = 0; mi < MI; ++mi)
      #pragma unroll
      for (int np = 0; np < MI/2; ++np) {
        const int ni = np*2;
        const int ocol = ((n0 + wc + ni*16) >> 5) * 16 + lr;
        #pragma unroll
        for (int r = 0; r < 4; ++r) {
          int row = m0 + wr + mi*16 + gg + r;
          if (row < M) {
            float g = acc[mi][ni][r], v = acc[mi][ni+1][r];
            float sl = g / (1.f + __expf(-g));
            ((short*)Cv)[(size_t)row * (N >> 1) + ocol] = f2bf(sl * v);
          }
        }
      }
  } else if constexpr (PREP != 0) {
    const int colsec = n0 + wc;              // wave-uniform
    const bool isv = (colsec >= 2048);
    const float* gp = (colsec < 1024) ? qg : kg;
    float gv[MI];
    if (!isv) {
      #pragma unroll
      for (int ni = 0; ni < MI; ++ni) gv[ni] = gp[ni*16 + lr];
    }
    #pragma unroll
    for (int mi = 0; mi < MI; ++mi) {
      #pragma unroll
      for (int r = 0; r < 4; ++r) {
        int row = m0 + wr + mi*16 + gg + r;
        int rowc = row < M ? row : M - 1;
        float vv[MI];
        #pragma unroll
        for (int ni = 0; ni < MI; ++ni) vv[ni] = acc[mi][ni][r];
        if (!isv) {
          float ss = vv[0]*vv[0] + vv[1]*vv[1] + vv[2]*vv[2] + vv[3]*vv[3];
          ss += __shfl_xor(ss, 1);
          ss += __shfl_xor(ss, 2);
          ss += __shfl_xor(ss, 4);
          ss += __shfl_xor(ss, 8);
          float sc = rsqrtf(ss * (1.f/64.f) + 1e-6f);
          int pos = (PREP == 1) ? (rowc % S_) : (rowc / S_);
          float c0 = ctab[pos*32 + lr],      s0 = stab[pos*32 + lr];
          float c1 = ctab[pos*32 + 16 + lr], s1 = stab[pos*32 + 16 + lr];
          float a0 = vv[0]*sc*gv[0], a1 = vv[1]*sc*gv[1];
          float a2 = vv[2]*sc*gv[2], a3 = vv[3]*sc*gv[3];
          vv[0] = a0*c0 - a2*s0;
          vv[1] = a1*c1 - a3*s1;
          vv[2] = a0*s0 + a2*c0;
          vv[3] = a1*s1 + a3*c1;
        }
        if (row < M) {
          #pragma unroll
          for (int ni = 0; ni < MI; ++ni)
            ((short*)Cv)[(size_t)row * N + n0 + wc + ni*16 + lr] = f2bf(vv[ni]);
        }
      }
    }
  } else {
    #pragma unroll
    for (int mi = 0; mi < MI; ++mi)
      #pragma unroll
      for (int ni = 0; ni < MI; ++ni) {
        int col = n0 + wc + ni*16 + lr;
        #pragma unroll
        for (int r = 0; r < 4; ++r) {
          int row = m0 + wr + mi*16 + gg + r;
          if (row < M) {
            float v = acc[mi][ni][r];
            if (BIAS) v += bias[col];
            size_t orow = ROWMAP ? (size_t)((row >> 8) * S_ + 6 + (row & 255)) : (size_t)row;
            size_t idx = orow * N + col;
            if (RESID == 1)       ((float*)Cv)[idx] += v;
            else if (OUT == 1)    ((short*)Cv)[idx]  = f2bf(v);
            else                  ((float*)Cv)[idx]  = v;
          }
        }
      }
  }
}

// ---------------------------------------------------------------- RMSNorm (wave per row)
template<int FINAL>
__global__ __launch_bounds__(256)
void rmsnorm_k(const float* __restrict__ x, const float* __restrict__ w, short* __restrict__ h)
{
  const int lane = threadIdx.x & 63;
  const int row = blockIdx.x*4 + (threadIdx.x >> 6);
  const int xrow = FINAL ? ((row >> 8) * S_ + 6 + (row & 255)) : row;
  const float* xp = x + (size_t)xrow*D_;
  float4 v[4];
  #pragma unroll
  for (int j = 0; j < 4; ++j) v[j] = *(const float4*)(xp + j*256 + lane*4);
  float ss = 0.f;
  #pragma unroll
  for (int j = 0; j < 4; ++j) ss += v[j].x*v[j].x + v[j].y*v[j].y + v[j].z*v[j].z + v[j].w*v[j].w;
  #pragma unroll
  for (int m = 1; m < 64; m <<= 1) ss += __shfl_xor(ss, m);
  const float sc = rsqrtf(ss * (1.f/1024.f) + 1e-6f);
  #pragma unroll
  for (int j = 0; j < 4; ++j) {
    float4 wv = *(const float4*)(w + j*256 + lane*4);
    s16x4 hv;
    hv[0] = f2bf(v[j].x*sc*wv.x); hv[1] = f2bf(v[j].y*sc*wv.y);
    hv[2] = f2bf(v[j].z*sc*wv.z); hv[3] = f2bf(v[j].w*sc*wv.w);
    *(s16x4*)(h + (size_t)row*D_ + j*256 + lane*4) = hv;
  }
}

// ---------------------------------------------------------------- rope tables
__global__ void rope_tab_k(float* __restrict__ ct, float* __restrict__ st, int npos)
{
  int i = blockIdx.x*256 + threadIdx.x;
  if (i >= npos*32) return;
  int pos = i >> 5, fi = i & 31;
  float ang = (float)pos * expf((float)fi * (-9.210340371976184f/32.f));
  float s, c; sincosf(ang, &s, &c);
  ct[i] = c; st[i] = s;
}

// ---------------------------------------------------------------- spatial attention
__global__ __launch_bounds__(256)
void attn_spatial_k(const short* __restrict__ qkv, short* __restrict__ o)
{
  __shared__ __align__(16) short Vt[64][296];
  __shared__ __align__(16) short Pl[4][16][296];
  const int tid = threadIdx.x;
  const int b = blockIdx.x;          // T*H = 256
  const int t = b >> 4, h = b & 15;
  const short* kbase = qkv + (size_t)t*S_*3072 + 1024 + h*64;
  const short* vbase = kbase + 1024;
  const s16x8 zv = {0,0,0,0,0,0,0,0};
  #pragma unroll
  for (int i = 0; i < 9; ++i) {
    int slot = tid + 256*i;
    if (slot < 2176) {
      int row = slot >> 3, c8 = (slot & 7) * 8;
      s16x8 v = zv;
      if (row < S_) v = *(const s16x8*)(vbase + (size_t)row*3072 + c8);
      #pragma unroll
      for (int j = 0; j < 8; ++j) Vt[c8 + j][row] = v[j];
    }
  }
  #pragma unroll
  for (int i = 0; i < 6; ++i) {
    int slot = tid + 256*i;
    Vt[slot / 24][272 + (slot % 24)] = 0;
  }
  if (tid < 64) o[(size_t)t*S_*D_ + h*64 + tid] = vbase[tid];
  __syncthreads();

  const int lane = tid & 63, wid = tid >> 6;
  const int lr = lane & 15, lk = (lane >> 4) * 8;
  const int gg = (lane >> 4) * 4;
  const f32x4 fzero = {0.f,0.f,0.f,0.f};

  for (int qt = wid; qt < 17; qt += 4) {
    int qrow = qt*16 + lr; if (qrow >= S_) qrow = 0;
    const short* qbase = qkv + (size_t)(t*S_ + qrow)*3072 + h*64;
    s16x8 qf0 = *(const s16x8*)(qbase + lk);
    s16x8 qf1 = *(const s16x8*)(qbase + 32 + lk);

    f32x4 lg[17];
    #pragma unroll
    for (int nt = 0; nt < 17; ++nt) lg[nt] = fzero;
    __builtin_amdgcn_s_setprio(1);
    #pragma unroll
    for (int nt = 0; nt < 17; ++nt) {
      int krow = nt*16 + lr; if (krow >= S_) krow = S_ - 1;
      s16x8 kf0 = *(const s16x8*)(kbase + (size_t)krow*3072 + lk);
      s16x8 kf1 = *(const s16x8*)(kbase + (size_t)krow*3072 + 32 + lk);
      lg[nt] = __builtin_amdgcn_mfma_f32_16x16x32_bf16(qf0, kf0, lg[nt], 0, 0, 0);
      lg[nt] = __builtin_amdgcn_mfma_f32_16x16x32_bf16(qf1, kf1, lg[nt], 0, 0, 0);
    }
    __builtin_amdgcn_s_setprio(0);
    #pragma unroll
    for (int r = 0; r < 4; ++r) {
      float mx = -1e30f;
      #pragma unroll
      for (int nt = 0; nt < 17; ++nt) {
        float v = softcap(lg[nt][r] * 0.125f);
        if (nt*16 + lr >= S_) v = -1e30f;
        lg[nt][r] = v;
        mx = fmaxf(mx, v);
      }
      mx = fmaxf(mx, __shfl_xor(mx, 1));
      mx = fmaxf(mx, __shfl_xor(mx, 2));
      mx = fmaxf(mx, __shfl_xor(mx, 4));
      mx = fmaxf(mx, __shfl_xor(mx, 8));
      float sum = 0.f;
      #pragma unroll
      for (int nt = 0; nt < 17; ++nt) { float pe = __expf(lg[nt][r] - mx); lg[nt][r] = pe; sum += pe; }
      sum += __shfl_xor(sum, 1);
      sum += __shfl_xor(sum, 2);
      sum += __shfl_xor(sum, 4);
      sum += __shfl_xor(sum, 8);
      float is = 1.f / sum;
      #pragma unroll
      for (int nt = 0; nt < 17; ++nt) Pl[wid][gg + r][nt*16 + lr] = f2bf(lg[nt][r] * is);
      Pl[wid][gg + r][272 + lr] = 0;
    }
    f32x4 oacc[4];
    #pragma unroll
    for (int ni = 0; ni < 4; ++ni) oacc[ni] = fzero;
    __builtin_amdgcn_s_setprio(1);
    #pragma unroll
    for (int ks = 0; ks < 9; ++ks) {
      s16x8 pf = *(const s16x8*)&Pl[wid][lr][ks*32 + lk];
      #pragma unroll
      for (int ni = 0; ni < 4; ++ni) {
        s16x8 vf = *(const s16x8*)&Vt[ni*16 + lr][ks*32 + lk];
        oacc[ni] = __builtin_amdgcn_mfma_f32_16x16x32_bf16(pf, vf, oacc[ni], 0, 0, 0);
      }
    }
    __builtin_amdgcn_s_setprio(0);
    #pragma unroll
    for (int ni = 0; ni < 4; ++ni)
      #pragma unroll
      for (int r = 0; r < 4; ++r) {
        int q = qt*16 + gg + r;
        if (q < S_ && q != 0) o[(size_t)(t*S_ + q)*D_ + h*64 + ni*16 + lr] = f2bf(oacc[ni][r]);
      }
  }
}

// ---------------------------------------------------------------- temporal attention
__global__ __launch_bounds__(256)
void attn_temporal_k(const short* __restrict__ qkv, short* __restrict__ o)
{
  __shared__ float Ql[4][16][68];
  __shared__ float Kl[4][16][68];
  __shared__ float Vl[4][16][68];
  __shared__ float Pl2[4][16][17];
  const int tid = threadIdx.x, lane = tid & 63, wid = tid >> 6;
  const int gw = blockIdx.x*4 + wid;
  const int s = gw >> 4, h = gw & 15;
  const int tt = lane >> 2, dp = (lane & 3) * 16;
  const short* base = qkv + (size_t)(tt*S_ + s)*3072 + h*64 + dp;
  #pragma unroll
  for (int part = 0; part < 3; ++part) {
    const short* bp = base + part*1024;
    s16x8 v0 = *(const s16x8*)(bp);
    s16x8 v1 = *(const s16x8*)(bp + 8);
    float* dst = (part == 0) ? &Ql[wid][tt][dp] : (part == 1) ? &Kl[wid][tt][dp] : &Vl[wid][tt][dp];
    #pragma unroll
    for (int j = 0; j < 8; ++j) { dst[j] = bf2f(v0[j]); dst[8 + j] = bf2f(v1[j]); }
  }
  __syncthreads();
  const int qr = lane >> 2;
  float qv[64];
  #pragma unroll
  for (int j = 0; j < 64; ++j) qv[j] = Ql[wid][qr][j];
  float pvals[4];
  #pragma unroll
  for (int i = 0; i < 4; ++i) {
    int kt = (lane & 3) + i*4;
    float d = 0.f;
    #pragma unroll
    for (int j = 0; j < 64; ++j) d += qv[j] * Kl[wid][kt][j];
    d *= 0.125f;
    d = softcap(d);
    bool keep = (kt <= qr) && (kt + 9 >= qr);
    pvals[i] = keep ? d : -1e30f;
  }
  float mx = fmaxf(fmaxf(pvals[0], pvals[1]), fmaxf(pvals[2], pvals[3]));
  mx = fmaxf(mx, __shfl_xor(mx, 1));
  mx = fmaxf(mx, __shfl_xor(mx, 2));
  float sum = 0.f;
  #pragma unroll
  for (int i = 0; i < 4; ++i) { pvals[i] = __expf(pvals[i] - mx); sum += pvals[i]; }
  sum += __shfl_xor(sum, 1);
  sum += __shfl_xor(sum, 2);
  float is = 1.f / sum;
  #pragma unroll
  for (int i = 0; i < 4; ++i) Pl2[wid][qr][(lane & 3) + i*4] = pvals[i] * is;
  __syncthreads();
  float acc[16];
  #pragma unroll
  for (int j = 0; j < 16; ++j) acc[j] = 0.f;
  #pragma unroll
  for (int kt = 0; kt < 16; ++kt) {
    float pv = Pl2[wid][qr][kt];
    #pragma unroll
    for (int j = 0; j < 16; ++j) acc[j] += pv * Vl[wid][kt][dp + j];
  }
  short* op = o + (size_t)(qr*S_ + s)*D_ + h*64 + dp;
  #pragma unroll
  for (int j = 0; j < 16; ++j) op[j] = f2bf(acc[j]);
}

// ---------------------------------------------------------------- conversions / prologue
struct CvtJobs {
  const float* src[10];
  short* dst[10];
  int end[10];
  int njobs;
};

__global__ void cvt_multi_k(CvtJobs jobs)
{
  int q = blockIdx.x*256 + threadIdx.x;
  int j = 0;
  while (j < jobs.njobs && q >= jobs.end[j]) ++j;
  if (j >= jobs.njobs) return;
  int base = (j == 0) ? 0 : jobs.end[j-1];
  size_t idx = (size_t)(q - base);
  float4 v = *(const float4*)(jobs.src[j] + idx*4);
  s16x4 ov; ov[0]=f2bf(v.x); ov[1]=f2bf(v.y); ov[2]=f2bf(v.z); ov[3]=f2bf(v.w);
  *(s16x4*)(jobs.dst[j] + idx*4) = ov;
}

__global__ void cvt_f32_bf16_k(const float* __restrict__ in, short* __restrict__ out, int n4)
{
  int i = blockIdx.x*256 + threadIdx.x;
  if (i >= n4) return;
  float4 v = *(const float4*)(in + (size_t)i*4);
  s16x4 ov; ov[0]=f2bf(v.x); ov[1]=f2bf(v.y); ov[2]=f2bf(v.z); ov[3]=f2bf(v.w);
  *(s16x4*)(out + (size_t)i*4) = ov;
}

// w12: permute rows so gate/val interleave in 16-blocks within 32 (fused swiglu epilogue)
__global__ void cvt_w12_k(const float* __restrict__ in, short* __restrict__ out)
{
  int pb = blockIdx.x;             // 8 layers * 8192 rows
  int l = pb >> 13, pr = pb & 8191;
  int c = pr >> 5, q = pr & 31;
  int orig = (q < 16) ? c*16 + q : DH_ + c*16 + (q - 16);
  const float* ip = in + ((size_t)l*8192 + orig)*1024 + threadIdx.x*4;
  short* op = out + ((size_t)l*8192 + pr)*1024 + threadIdx.x*4;
  float4 v = *(const float4*)ip;
  s16x4 ov; ov[0]=f2bf(v.x); ov[1]=f2bf(v.y); ov[2]=f2bf(v.z); ov[3]=f2bf(v.w);
  *(s16x4*)op = ov;
}

__global__ void timestep_embed_k(const float* __restrict__ sig, float* __restrict__ emb)
{
  int tid = threadIdx.x;
  int n = tid >> 4;
  int j0 = (tid & 15) * 16;
  float tv = sig[n];
  for (int j = j0; j < j0 + 16; ++j) {
    int half = j & 127;
    float freq = expf(-9.210340371976184f * (float)half / 128.f);
    float a = tv * freq;
    emb[n*256 + j] = (j < 128) ? cosf(a) : sinf(a);
  }
}

__global__ void noise_mlp1_k(const float* __restrict__ emb, const float* __restrict__ w1,
                             const float* __restrict__ b1, float* __restrict__ hid)
{
  const int o = blockIdx.x*256 + threadIdx.x;
  const int n = o >> 10, e = o & 1023;
  const float4* er = (const float4*)(emb + n*256);
  const float4* wr = (const float4*)(w1 + (size_t)e*256);
  float s = b1[e];
  for (int k = 0; k < 64; ++k) { float4 a = er[k]; float4 b = wr[k]; s += a.x*b.x + a.y*b.y + a.z*b.z + a.w*b.w; }
  hid[o] = s / (1.f + __expf(-s));
}

__global__ void noise_mlp2_k(const float* __restrict__ hid, const float* __restrict__ w2,
                             const float* __restrict__ b2, float* __restrict__ sg)
{
  const int o = blockIdx.x*256 + threadIdx.x;
  const int n = o >> 10, e = o & 1023;
  const float4* hr = (const float4*)(hid + n*1024);
  const float4* wr = (const float4*)(w2 + (size_t)e*1024);
  float s = b2[e];
  for (int k = 0; k < 256; ++k) { float4 a = hr[k]; float4 b = wr[k]; s += a.x*b.x + a.y*b.y + a.z*b.z + a.w*b.w; }
  sg[o] = s;
}

__global__ void act_embed_k(const float* __restrict__ actions, const float* __restrict__ base,
                            const float* __restrict__ apw, const float* __restrict__ apb,
                            float* __restrict__ ar)
{
  const int o = blockIdx.x*256 + threadIdx.x;
  const int n = o >> 10, e = o & 1023;
  float s = base[e] + apb[e];
  #pragma unroll
  for (int j = 0; j < 8; ++j) s += actions[n*8 + j] * apw[(size_t)e*8 + j];
  ar[o] = s;
}

__global__ void fill6_k(const float* __restrict__ sig, const float* __restrict__ act,
                        const float* __restrict__ reg, float* __restrict__ x)
{
  const int b = blockIdx.x;            // 16*6
  const int t = b / 6, s = b % 6;
  const int d = threadIdx.x * 4;
  float4 v;
  if (s == 0)      v = *(const float4*)(sig + t*D_ + d);
  else if (s == 1) v = *(const float4*)(act + t*D_ + d);
  else             v = *(const float4*)(reg + (s-2)*D_ + d);
  *(float4*)(x + (size_t)(t*S_ + s)*D_ + d) = v;
}

// ---------------------------------------------------------------- host
extern "C" void kernel_launch(void* const* d_in, const int* in_sizes, int n_in,
                              void* d_out, int out_size, void* d_ws, size_t ws_size,
                              hipStream_t stream)
{
  (void)in_sizes; (void)n_in; (void)out_size;
  const float* noisy   = (const float*)d_in[0];
  const float* sig_lv  = (const float*)d_in[1];
  const float* actions = (const float*)d_in[2];
  const float* in_proj = (const float*)d_in[3];
  const float* nw1     = (const float*)d_in[4];
  const float* nb1     = (const float*)d_in[5];
  const float* nw2     = (const float*)d_in[6];
  const float* nb2     = (const float*)d_in[7];
  const float* base_ae = (const float*)d_in[8];
  const float* apw     = (const float*)d_in[9];
  const float* apb     = (const float*)d_in[10];
  const float* regtok  = (const float*)d_in[11];
  const float* ln1w    = (const float*)d_in[12];
  const float* s_wqkv  = (const float*)d_in[13];
  const float* s_wo    = (const float*)d_in[14];
  const float* s_qg    = (const float*)d_in[15];
  const float* s_kg    = (const float*)d_in[16];
  const float* lntw    = (const float*)d_in[17];
  const float* t_wqkv  = (const float*)d_in[18];
  const float* t_wo    = (const float*)d_in[19];
  const float* t_qg    = (const float*)d_in[20];
  const float* t_kg    = (const float*)d_in[21];
  const float* ln2w    = (const float*)d_in[22];
  const float* w12     = (const float*)d_in[23];
  const float* w3      = (const float*)d_in[24];
  const float* fnw     = (const float*)d_in[25];
  const float* outw    = (const float*)d_in[26];
  const float* outb    = (const float*)d_in[27];

  char* p = (char*)d_ws;
  auto take = [&](size_t n) { char* r = p; p += n; return r; };
  float* x   = (float*)take((size_t)NTOK*D_*4);
  short* hb  = (short*)take((size_t)NTOK*D_*2);
  short* qkv = (short*)take((size_t)NTOK*3072*2);
  short* ob  = (short*)take((size_t)NTOK*D_*2);
  short* mb  = qkv;                               // spans qkv+ob exactly (NTOK*4096*2)
  short* nlb = (short*)take((size_t)4096*INDIM_*2);
  float* emb = (float*)take(16*256*4);
  float* hid = (float*)take(16*1024*4);
  float* sgb = (float*)take(16*1024*4);
  float* acr = (float*)take(16*1024*4);
  float* csS = (float*)take(S_*32*4);
  float* snS = (float*)take(S_*32*4);
  float* csT = (float*)take(16*32*4);
  float* snT = (float*)take(16*32*4);
  short* wqkv_s_bf = (short*)take((size_t)8*3*D_*D_*2);
  short* wo_s_bf   = (short*)take((size_t)8*D_*D_*2);
  short* wqkv_t_bf = (short*)take((size_t)2*3*D_*D_*2);
  short* wo_t_bf   = (short*)take((size_t)2*D_*D_*2);
  short* w12_bf    = (short*)take((size_t)8*2*DH_*D_*2);
  short* w3_bf     = (short*)take((size_t)8*D_*DH_*2);
  short* inp_bf    = (short*)take((size_t)D_*INDIM_*2);
  short* outw_bf   = (short*)take((size_t)INDIM_*D_*2);
  const size_t full_need = (size_t)(p - (char*)d_ws);
  const bool wb = ws_size >= full_need;

  if (wb) {
    CvtJobs jobs;
    int acc_q = 0, nj = 0;
    auto add = [&](const float* s, short* d, size_t elems) {
      jobs.src[nj] = s; jobs.dst[nj] = d;
      acc_q += (int)(elems / 4); jobs.end[nj] = acc_q; ++nj;
    };
    add(s_wqkv, wqkv_s_bf, (size_t)8*3*D_*D_);
    add(s_wo,   wo_s_bf,   (size_t)8*D_*D_);
    add(t_wqkv,                     wqkv_t_bf,                   (size_t)3*D_*D_);
    add(t_wqkv + (size_t)4*3*D_*D_, wqkv_t_bf + (size_t)3*D_*D_, (size_t)3*D_*D_);
    add(t_wo,                       wo_t_bf,                     (size_t)D_*D_);
    add(t_wo + (size_t)4*D_*D_,     wo_t_bf + (size_t)D_*D_,     (size_t)D_*D_);
    add(w3,   w3_bf,   (size_t)8*D_*DH_);
    add(in_proj, inp_bf, (size_t)D_*INDIM_);
    add(outw,    outw_bf,(size_t)INDIM_*D_);
    add(noisy,   nlb,    (size_t)4096*INDIM_);
    jobs.njobs = nj;
    cvt_multi_k<<<(acc_q + 255)/256, 256, 0, stream>>>(jobs);
    cvt_w12_k<<<65536, 256, 0, stream>>>(w12, w12_bf);
  } else {
    cvt_f32_bf16_k<<<3072, 256, 0, stream>>>(noisy, nlb, 4096*INDIM_/4);
  }
  rope_tab_k<<<33, 256, 0, stream>>>(csS, snS, S_);
  rope_tab_k<<<2,  256, 0, stream>>>(csT, snT, 16);

  // prologue
  timestep_embed_k<<<1, 256, 0, stream>>>(sig_lv, emb);
  noise_mlp1_k<<<64, 256, 0, stream>>>(emb, nw1, nb1, hid);
  noise_mlp2_k<<<64, 256, 0, stream>>>(hid, nw2, nb2, sgb);
  act_embed_k<<<64, 256, 0, stream>>>(actions, base_ae, apw, apb, acr);
  if (wb) gemm2<1,0,0,0,1,0,0,1><<<dim3(16,64), 256, 0, stream>>>(nlb, inp_bf,  nullptr, x, 4096, D_, INDIM_, nullptr, nullptr, nullptr, nullptr);
  else    gemm2<1,0,0,0,0,0,0,1><<<dim3(16,64), 256, 0, stream>>>(nlb, in_proj, nullptr, x, 4096, D_, INDIM_, nullptr, nullptr, nullptr, nullptr);
  fill6_k<<<96, 256, 0, stream>>>(sgb, acr, regtok, x);

  for (int l = 0; l < 8; ++l) {
    rmsnorm_k<0><<<NTOK/4, 256, 0, stream>>>(x, ln1w + l*D_, hb);
    if (wb) gemm2<0,0,0,1,1,0,1,0><<<dim3(24,33), 256, 0, stream>>>(hb, wqkv_s_bf + (size_t)l*3*D_*D_, nullptr, qkv, NTOK, 3*D_, D_, s_qg + l*HD_, s_kg + l*HD_, csS, snS);
    else    gemm2<0,0,0,1,0,0,1,0><<<dim3(24,33), 256, 0, stream>>>(hb, s_wqkv   + (size_t)l*3*D_*D_, nullptr, qkv, NTOK, 3*D_, D_, s_qg + l*HD_, s_kg + l*HD_, csS, snS);
    attn_spatial_k<<<256, 256, 0, stream>>>(qkv, ob);
    if (wb) gemm2<1,1,0,0,1,0,0,0><<<dim3(16,66), 256, 0, stream>>>(ob, wo_s_bf + (size_t)l*D_*D_, nullptr, x, NTOK, D_, D_, nullptr, nullptr, nullptr, nullptr);
    else    gemm2<1,1,0,0,0,0,0,0><<<dim3(16,66), 256, 0, stream>>>(ob, s_wo    + (size_t)l*D_*D_, nullptr, x, NTOK, D_, D_, nullptr, nullptr, nullptr, nullptr);
    if (l % 4 == 0) {
      const int ls = l / 4;
      rmsnorm_k<0><<<NTOK/4, 256, 0, stream>>>(x, lntw + l*D_, hb);
      if (wb) gemm2<0,0,0,1,1,0,2,0><<<dim3(24,33), 256, 0, stream>>>(hb, wqkv_t_bf + (size_t)ls*3*D_*D_, nullptr, qkv, NTOK, 3*D_, D_, t_qg + l*HD_, t_kg + l*HD_, csT, snT);
      else    gemm2<0,0,0,1,0,0,2,0><<<dim3(24,33), 256, 0, stream>>>(hb, t_wqkv    + (size_t)l*3*D_*D_,  nullptr, qkv, NTOK, 3*D_, D_, t_qg + l*HD_, t_kg + l*HD_, csT, snT);
      attn_temporal_k<<<1048, 256, 0, stream>>>(qkv, ob);
      if (wb) gemm2<1,1,0,0,1,0,0,0><<<dim3(16,66), 256, 0, stream>>>(ob, wo_t_bf + (size_t)ls*D_*D_, nullptr, x, NTOK, D_, D_, nullptr, nullptr, nullptr, nullptr);
      else    gemm2<1,1,0,0,0,0,0,0><<<dim3(16,66), 256, 0, stream>>>(ob, t_wo    + (size_t)l*D_*D_,  nullptr, x, NTOK, D_, D_, nullptr, nullptr, nullptr, nullptr);
    }
    rmsnorm_k<0><<<NTOK/4, 256, 0, stream>>>(x, ln2w + l*D_, hb);
    if (wb) gemm2<0,0,0,2,1,0,0,0><<<dim3(64,33), 256, 0, stream>>>(hb, w12_bf + (size_t)l*2*DH_*D_, nullptr, mb, NTOK, 2*DH_, D_, nullptr, nullptr, nullptr, nullptr);
    else    gemm2<0,0,0,2,0,1,0,0><<<dim3(64,33), 256, 0, stream>>>(hb, w12    + (size_t)l*2*DH_*D_, nullptr, mb, NTOK, 2*DH_, D_, nullptr, nullptr, nullptr, nullptr);
    if (wb) gemm2<1,1,0,0,1,0,0,0><<<dim3(16,66), 256, 0, stream>>>(mb, w3_bf + (size_t)l*D_*DH_, nullptr, x, NTOK, D_, DH_, nullptr, nullptr, nullptr, nullptr);
    else    gemm2<1,1,0,0,0,0,0,0><<<dim3(16,66), 256, 0, stream>>>(mb, w3    + (size_t)l*D_*DH_, nullptr, x, NTOK, D_, DH_, nullptr, nullptr, nullptr, nullptr);
  }
  rmsnorm_k<1><<<1024, 256, 0, stream>>>(x, fnw, hb);
  if (wb) gemm2<1,0,1,0,1,0,0,0><<<dim3(12,64), 256, 0, stream>>>(hb, outw_bf, outb, (float*)d_out, 4096, INDIM_, D_, nullptr, nullptr, nullptr, nullptr);
  else    gemm2<1,0,1,0,0,0,0,0><<<dim3(12,64), 256, 0, stream>>>(hb, outw,    outb, (float*)d_out, 4096, INDIM_, D_, nullptr, nullptr, nullptr, nullptr);
}

// Round 13
// 2775.123 us; speedup vs baseline: 1.0692x; 1.0142x over previous
//
#include <hip/hip_runtime.h>
#include <hip/hip_bf16.h>
#include <math.h>

#define T_ 16
#define S_ 262
#define D_ 1024
#define H_ 16
#define HD_ 64
#define DH_ 4096
#define NTOK (T_*S_)     // 4192
#define LTOK_ 256
#define INDIM_ 768

typedef __attribute__((ext_vector_type(4))) float f32x4;
typedef __attribute__((ext_vector_type(8))) short s16x8;
typedef __attribute__((ext_vector_type(4))) short s16x4;

__device__ __forceinline__ short f2bf(float f) {
  union { float f; unsigned u; } v; v.f = f;
  unsigned r = v.u + 0x7fffu + ((v.u >> 16) & 1u);
  return (short)(r >> 16);
}
__device__ __forceinline__ float bf2f(short h) {
  union { unsigned u; float f; } v; v.u = ((unsigned)(unsigned short)h) << 16;
  return v.f;
}
__device__ __forceinline__ float softcap(float x) {
  float z = __expf(x * (2.0f / 50.0f));
  return 50.0f * (z - 1.0f) / (z + 1.0f);
}
__device__ __forceinline__ void gload16(const void* g, void* l) {
  __builtin_amdgcn_global_load_lds((const __attribute__((address_space(1))) void*)g,
                                   (__attribute__((address_space(3))) void*)l, 16, 0, 0);
}

// ---------------------------------------------------------------- GEMM
// C[M,N] = A_bf16[M,K] * W[N,K]^T
// SMALL: 0 -> 128x128 tile; 1 -> 64x64 tile.
//   TILE-SIZE LESSON (R5-R10 A/B): skinny GEMMs (N<=1024, M~4224) MUST use 64²
//   (occupancy/TLP-bound: 128² -> 1 block/CU ~600us loss; BK=128 -> 5 blocks/CU
//   ~150us loss). Big GEMMs (qkv N=3072, w12 N=8192) use 128². BK=64 everywhere.
//   XCD swizzle: neutral (R7). 256² coarse 2-phase: negative (R9).
// OUT: 0 f32, 1 bf16, 2 fused-swiglu bf16 (out cols N/2)   RESID: 1 -> f32 +=
// PREP: 1 spatial qk rms+rope, 2 temporal (only with SMALL=0)
// ROWMAP: out row -> (row>>8)*S_+6+(row&255)
template<int SMALL, int RESID, int BIAS, int OUT, int WB, int PERM, int PREP, int ROWMAP>
__global__ __launch_bounds__(256)
void gemm2(const short* __restrict__ A, const void* __restrict__ Wv,
           const float* __restrict__ bias, void* __restrict__ Cv,
           int M, int N, int K,
           const float* __restrict__ qg, const float* __restrict__ kg,
           const float* __restrict__ ctab, const float* __restrict__ stab)
{
  constexpr int BM   = SMALL ? 64 : 128;
  constexpr int MI   = SMALL ? 2 : 4;     // 16x16 frags per wave per dim
  constexpr int WR   = SMALL ? 32 : 64;   // per-wave tile
  constexpr int NSTG = SMALL ? 2 : 4;     // staging iters (8 rows/wave each)
  __shared__ __align__(16) short As[BM*64];
  __shared__ __align__(16) short Bs[BM*64];
  const int tid = threadIdx.x;
  const int m0 = blockIdx.y * BM, n0 = blockIdx.x * BM;
  const int lane = tid & 63, wid = tid >> 6;
  const int wr = (wid >> 1) * WR, wc = (wid & 1) * WR;
  const int lr = lane & 15, lk = (lane >> 4) * 8;
  const short* Wb = (const short*)Wv;
  const float* Wf = (const float*)Wv;

  const f32x4 fzero = {0.f, 0.f, 0.f, 0.f};
  f32x4 acc[MI][MI];
  #pragma unroll
  for (int i = 0; i < MI; ++i)
    #pragma unroll
    for (int j = 0; j < MI; ++j) acc[i][j] = fzero;

  for (int k0 = 0; k0 < K; k0 += 64) {
    #pragma unroll
    for (int i = 0; i < NSTG; ++i) {         // A tile, swizzled global source
      int row = wid*(NSTG*8) + i*8 + (lane >> 3);
      int gm = m0 + row; if (gm >= M) gm = M - 1;
      int gc = (((lane & 7) ^ (row & 7)) << 3);
      gload16(A + (size_t)gm*K + k0 + gc, &As[(wid*(NSTG*8) + i*8)*64]);
    }
    if constexpr (WB) {
      #pragma unroll
      for (int i = 0; i < NSTG; ++i) {
        int row = wid*(NSTG*8) + i*8 + (lane >> 3);
        int gc = (((lane & 7) ^ (row & 7)) << 3);
        gload16(Wb + (size_t)(n0 + row)*K + k0 + gc, &Bs[(wid*(NSTG*8) + i*8)*64]);
      }
    } else {
      #pragma unroll
      for (int i = 0; i < NSTG; ++i) {       // fallback: reg-stage f32 -> bf16
        int slot = tid + 256*i;
        int row = slot >> 3, c8 = (slot & 7) << 3;
        int gr = n0 + row;
        if (PERM) { int c = gr >> 5, q = gr & 31; gr = (q < 16) ? c*16 + q : DH_ + c*16 + (q - 16); }
        const float* wp = Wf + (size_t)gr*K + k0 + c8;
        float4 w0 = *(const float4*)wp, w1 = *(const float4*)(wp + 4);
        s16x8 b;
        b[0]=f2bf(w0.x); b[1]=f2bf(w0.y); b[2]=f2bf(w0.z); b[3]=f2bf(w0.w);
        b[4]=f2bf(w1.x); b[5]=f2bf(w1.y); b[6]=f2bf(w1.z); b[7]=f2bf(w1.w);
        *(s16x8*)&Bs[row*64 + (c8 ^ ((row & 7) << 3))] = b;
      }
    }
    __syncthreads();
    #pragma unroll
    for (int kh = 0; kh < 2; ++kh) {
      const int col0 = kh*32 + lk;
      s16x8 af[MI], bfr[MI];
      #pragma unroll
      for (int mi = 0; mi < MI; ++mi) {
        int row = wr + mi*16 + lr;
        af[mi] = *(const s16x8*)&As[row*64 + (col0 ^ ((row & 7) << 3))];
      }
      #pragma unroll
      for (int ni = 0; ni < MI; ++ni) {
        int row = wc + ni*16 + lr;
        bfr[ni] = *(const s16x8*)&Bs[row*64 + (col0 ^ ((row & 7) << 3))];
      }
      #pragma unroll
      for (int mi = 0; mi < MI; ++mi)
        #pragma unroll
        for (int ni = 0; ni < MI; ++ni)
          acc[mi][ni] = __builtin_amdgcn_mfma_f32_16x16x32_bf16(af[mi], bfr[ni], acc[mi][ni], 0, 0, 0);
    }
    __syncthreads();
  }
  const int gg = (lane >> 4) * 4;
  if constexpr (OUT == 2) {
    #pragma unroll
    for (int mi = 0; mi < MI; ++mi)
      #pragma unroll
      for (int np = 0; np < MI/2; ++np) {
        const int ni = np*2;
        const int ocol = ((n0 + wc + ni*16) >> 5) * 16 + lr;
        #pragma unroll
        for (int r = 0; r < 4; ++r) {
          int row = m0 + wr + mi*16 + gg + r;
          if (row < M) {
            float g = acc[mi][ni][r], v = acc[mi][ni+1][r];
            float sl = g / (1.f + __expf(-g));
            ((short*)Cv)[(size_t)row * (N >> 1) + ocol] = f2bf(sl * v);
          }
        }
      }
  } else if constexpr (PREP != 0) {
    const int colsec = n0 + wc;              // wave-uniform
    const bool isv = (colsec >= 2048);
    const float* gp = (colsec < 1024) ? qg : kg;
    float gv[MI];
    if (!isv) {
      #pragma unroll
      for (int ni = 0; ni < MI; ++ni) gv[ni] = gp[ni*16 + lr];
    }
    #pragma unroll
    for (int mi = 0; mi < MI; ++mi) {
      #pragma unroll
      for (int r = 0; r < 4; ++r) {
        int row = m0 + wr + mi*16 + gg + r;
        int rowc = row < M ? row : M - 1;
        float vv[MI];
        #pragma unroll
        for (int ni = 0; ni < MI; ++ni) vv[ni] = acc[mi][ni][r];
        if (!isv) {
          float ss = vv[0]*vv[0] + vv[1]*vv[1] + vv[2]*vv[2] + vv[3]*vv[3];
          ss += __shfl_xor(ss, 1);
          ss += __shfl_xor(ss, 2);
          ss += __shfl_xor(ss, 4);
          ss += __shfl_xor(ss, 8);
          float sc = rsqrtf(ss * (1.f/64.f) + 1e-6f);
          int pos = (PREP == 1) ? (rowc % S_) : (rowc / S_);
          float c0 = ctab[pos*32 + lr],      s0 = stab[pos*32 + lr];
          float c1 = ctab[pos*32 + 16 + lr], s1 = stab[pos*32 + 16 + lr];
          float a0 = vv[0]*sc*gv[0], a1 = vv[1]*sc*gv[1];
          float a2 = vv[2]*sc*gv[2], a3 = vv[3]*sc*gv[3];
          vv[0] = a0*c0 - a2*s0;
          vv[1] = a1*c1 - a3*s1;
          vv[2] = a0*s0 + a2*c0;
          vv[3] = a1*s1 + a3*c1;
        }
        if (row < M) {
          #pragma unroll
          for (int ni = 0; ni < MI; ++ni)
            ((short*)Cv)[(size_t)row * N + n0 + wc + ni*16 + lr] = f2bf(vv[ni]);
        }
      }
    }
  } else {
    #pragma unroll
    for (int mi = 0; mi < MI; ++mi)
      #pragma unroll
      for (int ni = 0; ni < MI; ++ni) {
        int col = n0 + wc + ni*16 + lr;
        #pragma unroll
        for (int r = 0; r < 4; ++r) {
          int row = m0 + wr + mi*16 + gg + r;
          if (row < M) {
            float v = acc[mi][ni][r];
            if (BIAS) v += bias[col];
            size_t orow = ROWMAP ? (size_t)((row >> 8) * S_ + 6 + (row & 255)) : (size_t)row;
            size_t idx = orow * N + col;
            if (RESID == 1)       ((float*)Cv)[idx] += v;
            else if (OUT == 1)    ((short*)Cv)[idx]  = f2bf(v);
            else                  ((float*)Cv)[idx]  = v;
          }
        }
      }
  }
}

// ---------------------------------------------------------------- RMSNorm (wave per row)
template<int FINAL>
__global__ __launch_bounds__(256)
void rmsnorm_k(const float* __restrict__ x, const float* __restrict__ w, short* __restrict__ h)
{
  const int lane = threadIdx.x & 63;
  const int row = blockIdx.x*4 + (threadIdx.x >> 6);
  const int xrow = FINAL ? ((row >> 8) * S_ + 6 + (row & 255)) : row;
  const float* xp = x + (size_t)xrow*D_;
  float4 v[4];
  #pragma unroll
  for (int j = 0; j < 4; ++j) v[j] = *(const float4*)(xp + j*256 + lane*4);
  float ss = 0.f;
  #pragma unroll
  for (int j = 0; j < 4; ++j) ss += v[j].x*v[j].x + v[j].y*v[j].y + v[j].z*v[j].z + v[j].w*v[j].w;
  #pragma unroll
  for (int m = 1; m < 64; m <<= 1) ss += __shfl_xor(ss, m);
  const float sc = rsqrtf(ss * (1.f/1024.f) + 1e-6f);
  #pragma unroll
  for (int j = 0; j < 4; ++j) {
    float4 wv = *(const float4*)(w + j*256 + lane*4);
    s16x4 hv;
    hv[0] = f2bf(v[j].x*sc*wv.x); hv[1] = f2bf(v[j].y*sc*wv.y);
    hv[2] = f2bf(v[j].z*sc*wv.z); hv[3] = f2bf(v[j].w*sc*wv.w);
    *(s16x4*)(h + (size_t)row*D_ + j*256 + lane*4) = hv;
  }
}

// ---------------------------------------------------------------- rope tables
__global__ void rope_tab_k(float* __restrict__ ct, float* __restrict__ st, int npos)
{
  int i = blockIdx.x*256 + threadIdx.x;
  if (i >= npos*32) return;
  int pos = i >> 5, fi = i & 31;
  float ang = (float)pos * expf((float)fi * (-9.210340371976184f/32.f));
  float s, c; sincosf(ang, &s, &c);
  ct[i] = c; st[i] = s;
}

// ---------------------------------------------------------------- spatial attention
// softcap bounds logits to [-50,50] -> exp() cannot overflow f32; the softmax
// max-subtraction pass is dropped entirely (shift-invariance; masked -1e30 -> exp 0).
__global__ __launch_bounds__(256)
void attn_spatial_k(const short* __restrict__ qkv, short* __restrict__ o)
{
  __shared__ __align__(16) short Vt[64][296];
  __shared__ __align__(16) short Pl[4][16][296];
  const int tid = threadIdx.x;
  const int b = blockIdx.x;          // T*H = 256
  const int t = b >> 4, h = b & 15;
  const short* kbase = qkv + (size_t)t*S_*3072 + 1024 + h*64;
  const short* vbase = kbase + 1024;
  const s16x8 zv = {0,0,0,0,0,0,0,0};
  #pragma unroll
  for (int i = 0; i < 9; ++i) {
    int slot = tid + 256*i;
    if (slot < 2176) {
      int row = slot >> 3, c8 = (slot & 7) * 8;
      s16x8 v = zv;
      if (row < S_) v = *(const s16x8*)(vbase + (size_t)row*3072 + c8);
      #pragma unroll
      for (int j = 0; j < 8; ++j) Vt[c8 + j][row] = v[j];
    }
  }
  #pragma unroll
  for (int i = 0; i < 6; ++i) {
    int slot = tid + 256*i;
    Vt[slot / 24][272 + (slot % 24)] = 0;
  }
  if (tid < 64) o[(size_t)t*S_*D_ + h*64 + tid] = vbase[tid];
  __syncthreads();

  const int lane = tid & 63, wid = tid >> 6;
  const int lr = lane & 15, lk = (lane >> 4) * 8;
  const int gg = (lane >> 4) * 4;
  const f32x4 fzero = {0.f,0.f,0.f,0.f};

  for (int qt = wid; qt < 17; qt += 4) {
    int qrow = qt*16 + lr; if (qrow >= S_) qrow = 0;
    const short* qbase = qkv + (size_t)(t*S_ + qrow)*3072 + h*64;
    s16x8 qf0 = *(const s16x8*)(qbase + lk);
    s16x8 qf1 = *(const s16x8*)(qbase + 32 + lk);

    f32x4 lg[17];
    #pragma unroll
    for (int nt = 0; nt < 17; ++nt) lg[nt] = fzero;
    __builtin_amdgcn_s_setprio(1);
    #pragma unroll
    for (int nt = 0; nt < 17; ++nt) {
      int krow = nt*16 + lr; if (krow >= S_) krow = S_ - 1;
      s16x8 kf0 = *(const s16x8*)(kbase + (size_t)krow*3072 + lk);
      s16x8 kf1 = *(const s16x8*)(kbase + (size_t)krow*3072 + 32 + lk);
      lg[nt] = __builtin_amdgcn_mfma_f32_16x16x32_bf16(qf0, kf0, lg[nt], 0, 0, 0);
      lg[nt] = __builtin_amdgcn_mfma_f32_16x16x32_bf16(qf1, kf1, lg[nt], 0, 0, 0);
    }
    __builtin_amdgcn_s_setprio(0);
    #pragma unroll
    for (int r = 0; r < 4; ++r) {
      float sum = 0.f;
      #pragma unroll
      for (int nt = 0; nt < 17; ++nt) {
        float v = softcap(lg[nt][r] * 0.125f);
        float pe = (nt*16 + lr >= S_) ? 0.f : __expf(v);
        lg[nt][r] = pe;
        sum += pe;
      }
      sum += __shfl_xor(sum, 1);
      sum += __shfl_xor(sum, 2);
      sum += __shfl_xor(sum, 4);
      sum += __shfl_xor(sum, 8);
      float is = 1.f / sum;
      #pragma unroll
      for (int nt = 0; nt < 17; ++nt) Pl[wid][gg + r][nt*16 + lr] = f2bf(lg[nt][r] * is);
      Pl[wid][gg + r][272 + lr] = 0;
    }
    f32x4 oacc[4];
    #pragma unroll
    for (int ni = 0; ni < 4; ++ni) oacc[ni] = fzero;
    __builtin_amdgcn_s_setprio(1);
    #pragma unroll
    for (int ks = 0; ks < 9; ++ks) {
      s16x8 pf = *(const s16x8*)&Pl[wid][lr][ks*32 + lk];
      #pragma unroll
      for (int ni = 0; ni < 4; ++ni) {
        s16x8 vf = *(const s16x8*)&Vt[ni*16 + lr][ks*32 + lk];
        oacc[ni] = __builtin_amdgcn_mfma_f32_16x16x32_bf16(pf, vf, oacc[ni], 0, 0, 0);
      }
    }
    __builtin_amdgcn_s_setprio(0);
    #pragma unroll
    for (int ni = 0; ni < 4; ++ni)
      #pragma unroll
      for (int r = 0; r < 4; ++r) {
        int q = qt*16 + gg + r;
        if (q < S_ && q != 0) o[(size_t)(t*S_ + q)*D_ + h*64 + ni*16 + lr] = f2bf(oacc[ni][r]);
      }
  }
}

// ---------------------------------------------------------------- temporal attention
__global__ __launch_bounds__(256)
void attn_temporal_k(const short* __restrict__ qkv, short* __restrict__ o)
{
  __shared__ float Ql[4][16][68];
  __shared__ float Kl[4][16][68];
  __shared__ float Vl[4][16][68];
  __shared__ float Pl2[4][16][17];
  const int tid = threadIdx.x, lane = tid & 63, wid = tid >> 6;
  const int gw = blockIdx.x*4 + wid;
  const int s = gw >> 4, h = gw & 15;
  const int tt = lane >> 2, dp = (lane & 3) * 16;
  const short* base = qkv + (size_t)(tt*S_ + s)*3072 + h*64 + dp;
  #pragma unroll
  for (int part = 0; part < 3; ++part) {
    const short* bp = base + part*1024;
    s16x8 v0 = *(const s16x8*)(bp);
    s16x8 v1 = *(const s16x8*)(bp + 8);
    float* dst = (part == 0) ? &Ql[wid][tt][dp] : (part == 1) ? &Kl[wid][tt][dp] : &Vl[wid][tt][dp];
    #pragma unroll
    for (int j = 0; j < 8; ++j) { dst[j] = bf2f(v0[j]); dst[8 + j] = bf2f(v1[j]); }
  }
  __syncthreads();
  const int qr = lane >> 2;
  float qv[64];
  #pragma unroll
  for (int j = 0; j < 64; ++j) qv[j] = Ql[wid][qr][j];
  float pvals[4];
  #pragma unroll
  for (int i = 0; i < 4; ++i) {
    int kt = (lane & 3) + i*4;
    float d = 0.f;
    #pragma unroll
    for (int j = 0; j < 64; ++j) d += qv[j] * Kl[wid][kt][j];
    d *= 0.125f;
    d = softcap(d);                       // bounded to [-50,50] -> exp safe w/o max
    bool keep = (kt <= qr) && (kt + 9 >= qr);
    pvals[i] = keep ? __expf(d) : 0.f;
  }
  float sum = pvals[0] + pvals[1] + pvals[2] + pvals[3];
  sum += __shfl_xor(sum, 1);
  sum += __shfl_xor(sum, 2);
  float is = 1.f / sum;
  #pragma unroll
  for (int i = 0; i < 4; ++i) Pl2[wid][qr][(lane & 3) + i*4] = pvals[i] * is;
  __syncthreads();
  float acc[16];
  #pragma unroll
  for (int j = 0; j < 16; ++j) acc[j] = 0.f;
  #pragma unroll
  for (int kt = 0; kt < 16; ++kt) {
    float pv = Pl2[wid][qr][kt];
    #pragma unroll
    for (int j = 0; j < 16; ++j) acc[j] += pv * Vl[wid][kt][dp + j];
  }
  short* op = o + (size_t)(qr*S_ + s)*D_ + h*64 + dp;
  #pragma unroll
  for (int j = 0; j < 16; ++j) op[j] = f2bf(acc[j]);
}

// ---------------------------------------------------------------- conversions / prologue
struct CvtJobs {
  const float* src[10];
  short* dst[10];
  int end[10];
  int njobs;
};

__global__ void cvt_multi_k(CvtJobs jobs)
{
  int q = blockIdx.x*256 + threadIdx.x;
  int j = 0;
  while (j < jobs.njobs && q >= jobs.end[j]) ++j;
  if (j >= jobs.njobs) return;
  int base = (j == 0) ? 0 : jobs.end[j-1];
  size_t idx = (size_t)(q - base);
  float4 v = *(const float4*)(jobs.src[j] + idx*4);
  s16x4 ov; ov[0]=f2bf(v.x); ov[1]=f2bf(v.y); ov[2]=f2bf(v.z); ov[3]=f2bf(v.w);
  *(s16x4*)(jobs.dst[j] + idx*4) = ov;
}

__global__ void cvt_f32_bf16_k(const float* __restrict__ in, short* __restrict__ out, int n4)
{
  int i = blockIdx.x*256 + threadIdx.x;
  if (i >= n4) return;
  float4 v = *(const float4*)(in + (size_t)i*4);
  s16x4 ov; ov[0]=f2bf(v.x); ov[1]=f2bf(v.y); ov[2]=f2bf(v.z); ov[3]=f2bf(v.w);
  *(s16x4*)(out + (size_t)i*4) = ov;
}

// w12: permute rows so gate/val interleave in 16-blocks within 32 (fused swiglu epilogue)
__global__ void cvt_w12_k(const float* __restrict__ in, short* __restrict__ out)
{
  int pb = blockIdx.x;             // 8 layers * 8192 rows
  int l = pb >> 13, pr = pb & 8191;
  int c = pr >> 5, q = pr & 31;
  int orig = (q < 16) ? c*16 + q : DH_ + c*16 + (q - 16);
  const float* ip = in + ((size_t)l*8192 + orig)*1024 + threadIdx.x*4;
  short* op = out + ((size_t)l*8192 + pr)*1024 + threadIdx.x*4;
  float4 v = *(const float4*)ip;
  s16x4 ov; ov[0]=f2bf(v.x); ov[1]=f2bf(v.y); ov[2]=f2bf(v.z); ov[3]=f2bf(v.w);
  *(s16x4*)op = ov;
}

__global__ void timestep_embed_k(const float* __restrict__ sig, float* __restrict__ emb)
{
  int tid = threadIdx.x;
  int n = tid >> 4;
  int j0 = (tid & 15) * 16;
  float tv = sig[n];
  for (int j = j0; j < j0 + 16; ++j) {
    int half = j & 127;
    float freq = expf(-9.210340371976184f * (float)half / 128.f);
    float a = tv * freq;
    emb[n*256 + j] = (j < 128) ? cosf(a) : sinf(a);
  }
}

__global__ void noise_mlp1_k(const float* __restrict__ emb, const float* __restrict__ w1,
                             const float* __restrict__ b1, float* __restrict__ hid)
{
  const int o = blockIdx.x*256 + threadIdx.x;
  const int n = o >> 10, e = o & 1023;
  const float4* er = (const float4*)(emb + n*256);
  const float4* wr = (const float4*)(w1 + (size_t)e*256);
  float s = b1[e];
  for (int k = 0; k < 64; ++k) { float4 a = er[k]; float4 b = wr[k]; s += a.x*b.x + a.y*b.y + a.z*b.z + a.w*b.w; }
  hid[o] = s / (1.f + __expf(-s));
}

__global__ void noise_mlp2_k(const float* __restrict__ hid, const float* __restrict__ w2,
                             const float* __restrict__ b2, float* __restrict__ sg)
{
  const int o = blockIdx.x*256 + threadIdx.x;
  const int n = o >> 10, e = o & 1023;
  const float4* hr = (const float4*)(hid + n*1024);
  const float4* wr = (const float4*)(w2 + (size_t)e*1024);
  float s = b2[e];
  for (int k = 0; k < 256; ++k) { float4 a = hr[k]; float4 b = wr[k]; s += a.x*b.x + a.y*b.y + a.z*b.z + a.w*b.w; }
  sg[o] = s;
}

__global__ void act_embed_k(const float* __restrict__ actions, const float* __restrict__ base,
                            const float* __restrict__ apw, const float* __restrict__ apb,
                            float* __restrict__ ar)
{
  const int o = blockIdx.x*256 + threadIdx.x;
  const int n = o >> 10, e = o & 1023;
  float s = base[e] + apb[e];
  #pragma unroll
  for (int j = 0; j < 8; ++j) s += actions[n*8 + j] * apw[(size_t)e*8 + j];
  ar[o] = s;
}

__global__ void fill6_k(const float* __restrict__ sig, const float* __restrict__ act,
                        const float* __restrict__ reg, float* __restrict__ x)
{
  const int b = blockIdx.x;            // 16*6
  const int t = b / 6, s = b % 6;
  const int d = threadIdx.x * 4;
  float4 v;
  if (s == 0)      v = *(const float4*)(sig + t*D_ + d);
  else if (s == 1) v = *(const float4*)(act + t*D_ + d);
  else             v = *(const float4*)(reg + (s-2)*D_ + d);
  *(float4*)(x + (size_t)(t*S_ + s)*D_ + d) = v;
}

// ---------------------------------------------------------------- host
extern "C" void kernel_launch(void* const* d_in, const int* in_sizes, int n_in,
                              void* d_out, int out_size, void* d_ws, size_t ws_size,
                              hipStream_t stream)
{
  (void)in_sizes; (void)n_in; (void)out_size;
  const float* noisy   = (const float*)d_in[0];
  const float* sig_lv  = (const float*)d_in[1];
  const float* actions = (const float*)d_in[2];
  const float* in_proj = (const float*)d_in[3];
  const float* nw1     = (const float*)d_in[4];
  const float* nb1     = (const float*)d_in[5];
  const float* nw2     = (const float*)d_in[6];
  const float* nb2     = (const float*)d_in[7];
  const float* base_ae = (const float*)d_in[8];
  const float* apw     = (const float*)d_in[9];
  const float* apb     = (const float*)d_in[10];
  const float* regtok  = (const float*)d_in[11];
  const float* ln1w    = (const float*)d_in[12];
  const float* s_wqkv  = (const float*)d_in[13];
  const float* s_wo    = (const float*)d_in[14];
  const float* s_qg    = (const float*)d_in[15];
  const float* s_kg    = (const float*)d_in[16];
  const float* lntw    = (const float*)d_in[17];
  const float* t_wqkv  = (const float*)d_in[18];
  const float* t_wo    = (const float*)d_in[19];
  const float* t_qg    = (const float*)d_in[20];
  const float* t_kg    = (const float*)d_in[21];
  const float* ln2w    = (const float*)d_in[22];
  const float* w12     = (const float*)d_in[23];
  const float* w3      = (const float*)d_in[24];
  const float* fnw     = (const float*)d_in[25];
  const float* outw    = (const float*)d_in[26];
  const float* outb    = (const float*)d_in[27];

  char* p = (char*)d_ws;
  auto take = [&](size_t n) { char* r = p; p += n; return r; };
  float* x   = (float*)take((size_t)NTOK*D_*4);
  short* hb  = (short*)take((size_t)NTOK*D_*2);
  short* qkv = (short*)take((size_t)NTOK*3072*2);
  short* ob  = (short*)take((size_t)NTOK*D_*2);
  short* mb  = qkv;                               // spans qkv+ob exactly (NTOK*4096*2)
  short* nlb = (short*)take((size_t)4096*INDIM_*2);
  float* emb = (float*)take(16*256*4);
  float* hid = (float*)take(16*1024*4);
  float* sgb = (float*)take(16*1024*4);
  float* acr = (float*)take(16*1024*4);
  float* csS = (float*)take(S_*32*4);
  float* snS = (float*)take(S_*32*4);
  float* csT = (float*)take(16*32*4);
  float* snT = (float*)take(16*32*4);
  short* wqkv_s_bf = (short*)take((size_t)8*3*D_*D_*2);
  short* wo_s_bf   = (short*)take((size_t)8*D_*D_*2);
  short* wqkv_t_bf = (short*)take((size_t)2*3*D_*D_*2);
  short* wo_t_bf   = (short*)take((size_t)2*D_*D_*2);
  short* w12_bf    = (short*)take((size_t)8*2*DH_*D_*2);
  short* w3_bf     = (short*)take((size_t)8*D_*DH_*2);
  short* inp_bf    = (short*)take((size_t)D_*INDIM_*2);
  short* outw_bf   = (short*)take((size_t)INDIM_*D_*2);
  const size_t full_need = (size_t)(p - (char*)d_ws);
  const bool wb = ws_size >= full_need;

  if (wb) {
    CvtJobs jobs;
    int acc_q = 0, nj = 0;
    auto add = [&](const float* s, short* d, size_t elems) {
      jobs.src[nj] = s; jobs.dst[nj] = d;
      acc_q += (int)(elems / 4); jobs.end[nj] = acc_q; ++nj;
    };
    add(s_wqkv, wqkv_s_bf, (size_t)8*3*D_*D_);
    add(s_wo,   wo_s_bf,   (size_t)8*D_*D_);
    add(t_wqkv,                     wqkv_t_bf,                   (size_t)3*D_*D_);
    add(t_wqkv + (size_t)4*3*D_*D_, wqkv_t_bf + (size_t)3*D_*D_, (size_t)3*D_*D_);
    add(t_wo,                       wo_t_bf,                     (size_t)D_*D_);
    add(t_wo + (size_t)4*D_*D_,     wo_t_bf + (size_t)D_*D_,     (size_t)D_*D_);
    add(w3,   w3_bf,   (size_t)8*D_*DH_);
    add(in_proj, inp_bf, (size_t)D_*INDIM_);
    add(outw,    outw_bf,(size_t)INDIM_*D_);
    add(noisy,   nlb,    (size_t)4096*INDIM_);
    jobs.njobs = nj;
    cvt_multi_k<<<(acc_q + 255)/256, 256, 0, stream>>>(jobs);
    cvt_w12_k<<<65536, 256, 0, stream>>>(w12, w12_bf);
  } else {
    cvt_f32_bf16_k<<<3072, 256, 0, stream>>>(noisy, nlb, 4096*INDIM_/4);
  }
  rope_tab_k<<<33, 256, 0, stream>>>(csS, snS, S_);
  rope_tab_k<<<2,  256, 0, stream>>>(csT, snT, 16);

  // prologue
  timestep_embed_k<<<1, 256, 0, stream>>>(sig_lv, emb);
  noise_mlp1_k<<<64, 256, 0, stream>>>(emb, nw1, nb1, hid);
  noise_mlp2_k<<<64, 256, 0, stream>>>(hid, nw2, nb2, sgb);
  act_embed_k<<<64, 256, 0, stream>>>(actions, base_ae, apw, apb, acr);
  if (wb) gemm2<1,0,0,0,1,0,0,1><<<dim3(16,64), 256, 0, stream>>>(nlb, inp_bf,  nullptr, x, 4096, D_, INDIM_, nullptr, nullptr, nullptr, nullptr);
  else    gemm2<1,0,0,0,0,0,0,1><<<dim3(16,64), 256, 0, stream>>>(nlb, in_proj, nullptr, x, 4096, D_, INDIM_, nullptr, nullptr, nullptr, nullptr);
  fill6_k<<<96, 256, 0, stream>>>(sgb, acr, regtok, x);

  for (int l = 0; l < 8; ++l) {
    rmsnorm_k<0><<<NTOK/4, 256, 0, stream>>>(x, ln1w + l*D_, hb);
    if (wb) gemm2<0,0,0,1,1,0,1,0><<<dim3(24,33), 256, 0, stream>>>(hb, wqkv_s_bf + (size_t)l*3*D_*D_, nullptr, qkv, NTOK, 3*D_, D_, s_qg + l*HD_, s_kg + l*HD_, csS, snS);
    else    gemm2<0,0,0,1,0,0,1,0><<<dim3(24,33), 256, 0, stream>>>(hb, s_wqkv   + (size_t)l*3*D_*D_, nullptr, qkv, NTOK, 3*D_, D_, s_qg + l*HD_, s_kg + l*HD_, csS, snS);
    attn_spatial_k<<<256, 256, 0, stream>>>(qkv, ob);
    if (wb) gemm2<1,1,0,0,1,0,0,0><<<dim3(16,66), 256, 0, stream>>>(ob, wo_s_bf + (size_t)l*D_*D_, nullptr, x, NTOK, D_, D_, nullptr, nullptr, nullptr, nullptr);
    else    gemm2<1,1,0,0,0,0,0,0><<<dim3(16,66), 256, 0, stream>>>(ob, s_wo    + (size_t)l*D_*D_, nullptr, x, NTOK, D_, D_, nullptr, nullptr, nullptr, nullptr);
    if (l % 4 == 0) {
      const int ls = l / 4;
      rmsnorm_k<0><<<NTOK/4, 256, 0, stream>>>(x, lntw + l*D_, hb);
      if (wb) gemm2<0,0,0,1,1,0,2,0><<<dim3(24,33), 256, 0, stream>>>(hb, wqkv_t_bf + (size_t)ls*3*D_*D_, nullptr, qkv, NTOK, 3*D_, D_, t_qg + l*HD_, t_kg + l*HD_, csT, snT);
      else    gemm2<0,0,0,1,0,0,2,0><<<dim3(24,33), 256, 0, stream>>>(hb, t_wqkv    + (size_t)l*3*D_*D_,  nullptr, qkv, NTOK, 3*D_, D_, t_qg + l*HD_, t_kg + l*HD_, csT, snT);
      attn_temporal_k<<<1048, 256, 0, stream>>>(qkv, ob);
      if (wb) gemm2<1,1,0,0,1,0,0,0><<<dim3(16,66), 256, 0, stream>>>(ob, wo_t_bf + (size_t)ls*D_*D_, nullptr, x, NTOK, D_, D_, nullptr, nullptr, nullptr, nullptr);
      else    gemm2<1,1,0,0,0,0,0,0><<<dim3(16,66), 256, 0, stream>>>(ob, t_wo    + (size_t)l*D_*D_,  nullptr, x, NTOK, D_, D_, nullptr, nullptr, nullptr, nullptr);
    }
    rmsnorm_k<0><<<NTOK/4, 256, 0, stream>>>(x, ln2w + l*D_, hb);
    if (wb) gemm2<0,0,0,2,1,0,0,0><<<dim3(64,33), 256, 0, stream>>>(hb, w12_bf + (size_t)l*2*DH_*D_, nullptr, mb, NTOK, 2*DH_, D_, nullptr, nullptr, nullptr, nullptr);
    else    gemm2<0,0,0,2,0,1,0,0><<<dim3(64,33), 256, 0, stream>>>(hb, w12    + (size_t)l*2*DH_*D_, nullptr, mb, NTOK, 2*DH_, D_, nullptr, nullptr, nullptr, nullptr);
    if (wb) gemm2<1,1,0,0,1,0,0,0><<<dim3(16,66), 256, 0, stream>>>(mb, w3_bf + (size_t)l*D_*DH_, nullptr, x, NTOK, D_, DH_, nullptr, nullptr, nullptr, nullptr);
    else    gemm2<1,1,0,0,0,0,0,0><<<dim3(16,66), 256, 0, stream>>>(mb, w3    + (size_t)l*D_*DH_, nullptr, x, NTOK, D_, DH_, nullptr, nullptr, nullptr, nullptr);
  }
  rmsnorm_k<1><<<1024, 256, 0, stream>>>(x, fnw, hb);
  if (wb) gemm2<1,0,1,0,1,0,0,0><<<dim3(12,64), 256, 0, stream>>>(hb, outw_bf, outb, (float*)d_out, 4096, INDIM_, D_, nullptr, nullptr, nullptr, nullptr);
  else    gemm2<1,0,1,0,0,0,0,0><<<dim3(12,64), 256, 0, stream>>>(hb, outw,    outb, (float*)d_out, 4096, INDIM_, D_, nullptr, nullptr, nullptr, nullptr);
}

// Round 14
// 2764.277 us; speedup vs baseline: 1.0734x; 1.0039x over previous
//
#include <hip/hip_runtime.h>
#include <hip/hip_bf16.h>
#include <math.h>

#define T_ 16
#define S_ 262
#define D_ 1024
#define H_ 16
#define HD_ 64
#define DH_ 4096
#define NTOK (T_*S_)     // 4192
#define LTOK_ 256
#define INDIM_ 768

typedef __attribute__((ext_vector_type(4))) float f32x4;
typedef __attribute__((ext_vector_type(8))) short s16x8;
typedef __attribute__((ext_vector_type(4))) short s16x4;

__device__ __forceinline__ short f2bf(float f) {
  union { float f; unsigned u; } v; v.f = f;
  unsigned r = v.u + 0x7fffu + ((v.u >> 16) & 1u);
  return (short)(r >> 16);
}
__device__ __forceinline__ float bf2f(short h) {
  union { unsigned u; float f; } v; v.u = ((unsigned)(unsigned short)h) << 16;
  return v.f;
}
__device__ __forceinline__ float softcap(float x) {
  float z = __expf(x * (2.0f / 50.0f));
  return 50.0f * (z - 1.0f) / (z + 1.0f);
}
__device__ __forceinline__ void gload16(const void* g, void* l) {
  __builtin_amdgcn_global_load_lds((const __attribute__((address_space(1))) void*)g,
                                   (__attribute__((address_space(3))) void*)l, 16, 0, 0);
}

// ---------------------------------------------------------------- GEMM
// C[M,N] = A_bf16[M,K] * W[N,K]^T
// SMALL: 0 -> 128x128 tile; 1 -> 64x64 tile.
//   TILE-SIZE LESSON (R5-R10 A/B): skinny GEMMs (N<=1024, M~4224) MUST use 64²
//   (occupancy/TLP-bound: 128² -> 1 block/CU ~600us loss; BK=128 -> 5 blocks/CU
//   ~150us loss). Big GEMMs (qkv N=3072, w12 N=8192) use 128². BK=64 everywhere.
//   XCD swizzle: neutral (R7). 256² coarse 2-phase: negative (R9).
// OUT: 0 f32, 1 bf16, 2 fused-swiglu bf16 (out cols N/2)   RESID: 1 -> f32 +=
// PREP: 1 spatial qk rms+rope, 2 temporal (only with SMALL=0)
// ROWMAP: out row -> (row>>8)*S_+6+(row&255)
template<int SMALL, int RESID, int BIAS, int OUT, int WB, int PERM, int PREP, int ROWMAP>
__global__ __launch_bounds__(256)
void gemm2(const short* __restrict__ A, const void* __restrict__ Wv,
           const float* __restrict__ bias, void* __restrict__ Cv,
           int M, int N, int K,
           const float* __restrict__ qg, const float* __restrict__ kg,
           const float* __restrict__ ctab, const float* __restrict__ stab)
{
  constexpr int BM   = SMALL ? 64 : 128;
  constexpr int MI   = SMALL ? 2 : 4;     // 16x16 frags per wave per dim
  constexpr int WR   = SMALL ? 32 : 64;   // per-wave tile
  constexpr int NSTG = SMALL ? 2 : 4;     // staging iters (8 rows/wave each)
  __shared__ __align__(16) short As[BM*64];
  __shared__ __align__(16) short Bs[BM*64];
  const int tid = threadIdx.x;
  const int m0 = blockIdx.y * BM, n0 = blockIdx.x * BM;
  const int lane = tid & 63, wid = tid >> 6;
  const int wr = (wid >> 1) * WR, wc = (wid & 1) * WR;
  const int lr = lane & 15, lk = (lane >> 4) * 8;
  const short* Wb = (const short*)Wv;
  const float* Wf = (const float*)Wv;

  const f32x4 fzero = {0.f, 0.f, 0.f, 0.f};
  f32x4 acc[MI][MI];
  #pragma unroll
  for (int i = 0; i < MI; ++i)
    #pragma unroll
    for (int j = 0; j < MI; ++j) acc[i][j] = fzero;

  for (int k0 = 0; k0 < K; k0 += 64) {
    #pragma unroll
    for (int i = 0; i < NSTG; ++i) {         // A tile, swizzled global source
      int row = wid*(NSTG*8) + i*8 + (lane >> 3);
      int gm = m0 + row; if (gm >= M) gm = M - 1;
      int gc = (((lane & 7) ^ (row & 7)) << 3);
      gload16(A + (size_t)gm*K + k0 + gc, &As[(wid*(NSTG*8) + i*8)*64]);
    }
    if constexpr (WB) {
      #pragma unroll
      for (int i = 0; i < NSTG; ++i) {
        int row = wid*(NSTG*8) + i*8 + (lane >> 3);
        int gc = (((lane & 7) ^ (row & 7)) << 3);
        gload16(Wb + (size_t)(n0 + row)*K + k0 + gc, &Bs[(wid*(NSTG*8) + i*8)*64]);
      }
    } else {
      #pragma unroll
      for (int i = 0; i < NSTG; ++i) {       // fallback: reg-stage f32 -> bf16
        int slot = tid + 256*i;
        int row = slot >> 3, c8 = (slot & 7) << 3;
        int gr = n0 + row;
        if (PERM) { int c = gr >> 5, q = gr & 31; gr = (q < 16) ? c*16 + q : DH_ + c*16 + (q - 16); }
        const float* wp = Wf + (size_t)gr*K + k0 + c8;
        float4 w0 = *(const float4*)wp, w1 = *(const float4*)(wp + 4);
        s16x8 b;
        b[0]=f2bf(w0.x); b[1]=f2bf(w0.y); b[2]=f2bf(w0.z); b[3]=f2bf(w0.w);
        b[4]=f2bf(w1.x); b[5]=f2bf(w1.y); b[6]=f2bf(w1.z); b[7]=f2bf(w1.w);
        *(s16x8*)&Bs[row*64 + (c8 ^ ((row & 7) << 3))] = b;
      }
    }
    __syncthreads();
    #pragma unroll
    for (int kh = 0; kh < 2; ++kh) {
      const int col0 = kh*32 + lk;
      s16x8 af[MI], bfr[MI];
      #pragma unroll
      for (int mi = 0; mi < MI; ++mi) {
        int row = wr + mi*16 + lr;
        af[mi] = *(const s16x8*)&As[row*64 + (col0 ^ ((row & 7) << 3))];
      }
      #pragma unroll
      for (int ni = 0; ni < MI; ++ni) {
        int row = wc + ni*16 + lr;
        bfr[ni] = *(const s16x8*)&Bs[row*64 + (col0 ^ ((row & 7) << 3))];
      }
      #pragma unroll
      for (int mi = 0; mi < MI; ++mi)
        #pragma unroll
        for (int ni = 0; ni < MI; ++ni)
          acc[mi][ni] = __builtin_amdgcn_mfma_f32_16x16x32_bf16(af[mi], bfr[ni], acc[mi][ni], 0, 0, 0);
    }
    __syncthreads();
  }
  const int gg = (lane >> 4) * 4;
  if constexpr (OUT == 2) {
    #pragma unroll
    for (int mi = 0; mi < MI; ++mi)
      #pragma unroll
      for (int np = 0; np < MI/2; ++np) {
        const int ni = np*2;
        const int ocol = ((n0 + wc + ni*16) >> 5) * 16 + lr;
        #pragma unroll
        for (int r = 0; r < 4; ++r) {
          int row = m0 + wr + mi*16 + gg + r;
          if (row < M) {
            float g = acc[mi][ni][r], v = acc[mi][ni+1][r];
            float sl = g / (1.f + __expf(-g));
            ((short*)Cv)[(size_t)row * (N >> 1) + ocol] = f2bf(sl * v);
          }
        }
      }
  } else if constexpr (PREP != 0) {
    const int colsec = n0 + wc;              // wave-uniform
    const bool isv = (colsec >= 2048);
    const float* gp = (colsec < 1024) ? qg : kg;
    float gv[MI];
    if (!isv) {
      #pragma unroll
      for (int ni = 0; ni < MI; ++ni) gv[ni] = gp[ni*16 + lr];
    }
    #pragma unroll
    for (int mi = 0; mi < MI; ++mi) {
      #pragma unroll
      for (int r = 0; r < 4; ++r) {
        int row = m0 + wr + mi*16 + gg + r;
        int rowc = row < M ? row : M - 1;
        float vv[MI];
        #pragma unroll
        for (int ni = 0; ni < MI; ++ni) vv[ni] = acc[mi][ni][r];
        if (!isv) {
          float ss = vv[0]*vv[0] + vv[1]*vv[1] + vv[2]*vv[2] + vv[3]*vv[3];
          ss += __shfl_xor(ss, 1);
          ss += __shfl_xor(ss, 2);
          ss += __shfl_xor(ss, 4);
          ss += __shfl_xor(ss, 8);
          float sc = rsqrtf(ss * (1.f/64.f) + 1e-6f);
          int pos = (PREP == 1) ? (rowc % S_) : (rowc / S_);
          float c0 = ctab[pos*32 + lr],      s0 = stab[pos*32 + lr];
          float c1 = ctab[pos*32 + 16 + lr], s1 = stab[pos*32 + 16 + lr];
          float a0 = vv[0]*sc*gv[0], a1 = vv[1]*sc*gv[1];
          float a2 = vv[2]*sc*gv[2], a3 = vv[3]*sc*gv[3];
          vv[0] = a0*c0 - a2*s0;
          vv[1] = a1*c1 - a3*s1;
          vv[2] = a0*s0 + a2*c0;
          vv[3] = a1*s1 + a3*c1;
        }
        if (row < M) {
          #pragma unroll
          for (int ni = 0; ni < MI; ++ni)
            ((short*)Cv)[(size_t)row * N + n0 + wc + ni*16 + lr] = f2bf(vv[ni]);
        }
      }
    }
  } else {
    #pragma unroll
    for (int mi = 0; mi < MI; ++mi)
      #pragma unroll
      for (int ni = 0; ni < MI; ++ni) {
        int col = n0 + wc + ni*16 + lr;
        #pragma unroll
        for (int r = 0; r < 4; ++r) {
          int row = m0 + wr + mi*16 + gg + r;
          if (row < M) {
            float v = acc[mi][ni][r];
            if (BIAS) v += bias[col];
            size_t orow = ROWMAP ? (size_t)((row >> 8) * S_ + 6 + (row & 255)) : (size_t)row;
            size_t idx = orow * N + col;
            if (RESID == 1)       ((float*)Cv)[idx] += v;
            else if (OUT == 1)    ((short*)Cv)[idx]  = f2bf(v);
            else                  ((float*)Cv)[idx]  = v;
          }
        }
      }
  }
}

// ---------------------------------------------------------------- RMSNorm (wave per row)
template<int FINAL>
__global__ __launch_bounds__(256)
void rmsnorm_k(const float* __restrict__ x, const float* __restrict__ w, short* __restrict__ h)
{
  const int lane = threadIdx.x & 63;
  const int row = blockIdx.x*4 + (threadIdx.x >> 6);
  const int xrow = FINAL ? ((row >> 8) * S_ + 6 + (row & 255)) : row;
  const float* xp = x + (size_t)xrow*D_;
  float4 v[4];
  #pragma unroll
  for (int j = 0; j < 4; ++j) v[j] = *(const float4*)(xp + j*256 + lane*4);
  float ss = 0.f;
  #pragma unroll
  for (int j = 0; j < 4; ++j) ss += v[j].x*v[j].x + v[j].y*v[j].y + v[j].z*v[j].z + v[j].w*v[j].w;
  #pragma unroll
  for (int m = 1; m < 64; m <<= 1) ss += __shfl_xor(ss, m);
  const float sc = rsqrtf(ss * (1.f/1024.f) + 1e-6f);
  #pragma unroll
  for (int j = 0; j < 4; ++j) {
    float4 wv = *(const float4*)(w + j*256 + lane*4);
    s16x4 hv;
    hv[0] = f2bf(v[j].x*sc*wv.x); hv[1] = f2bf(v[j].y*sc*wv.y);
    hv[2] = f2bf(v[j].z*sc*wv.z); hv[3] = f2bf(v[j].w*sc*wv.w);
    *(s16x4*)(h + (size_t)row*D_ + j*256 + lane*4) = hv;
  }
}

// ---------------------------------------------------------------- rope tables
__global__ void rope_tab_k(float* __restrict__ ct, float* __restrict__ st, int npos)
{
  int i = blockIdx.x*256 + threadIdx.x;
  if (i >= npos*32) return;
  int pos = i >> 5, fi = i & 31;
  float ang = (float)pos * expf((float)fi * (-9.210340371976184f/32.f));
  float s, c; sincosf(ang, &s, &c);
  ct[i] = c; st[i] = s;
}

// ---------------------------------------------------------------- spatial attention
// softcap bounds logits to [-50,50] -> no max-subtraction needed (R13, -40us).
// P stored UNNORMALIZED (raw exp, <= e^50, safe in bf16); 1/sum folded into the
// PV accumulator epilogue (16 muls/lane/tile vs 68) -- PV is linear so identical.
__global__ __launch_bounds__(256)
void attn_spatial_k(const short* __restrict__ qkv, short* __restrict__ o)
{
  __shared__ __align__(16) short Vt[64][296];
  __shared__ __align__(16) short Pl[4][16][296];
  const int tid = threadIdx.x;
  const int b = blockIdx.x;          // T*H = 256
  const int t = b >> 4, h = b & 15;
  const short* kbase = qkv + (size_t)t*S_*3072 + 1024 + h*64;
  const short* vbase = kbase + 1024;
  const s16x8 zv = {0,0,0,0,0,0,0,0};
  #pragma unroll
  for (int i = 0; i < 9; ++i) {
    int slot = tid + 256*i;
    if (slot < 2176) {
      int row = slot >> 3, c8 = (slot & 7) * 8;
      s16x8 v = zv;
      if (row < S_) v = *(const s16x8*)(vbase + (size_t)row*3072 + c8);
      #pragma unroll
      for (int j = 0; j < 8; ++j) Vt[c8 + j][row] = v[j];
    }
  }
  #pragma unroll
  for (int i = 0; i < 6; ++i) {
    int slot = tid + 256*i;
    Vt[slot / 24][272 + (slot % 24)] = 0;
  }
  if (tid < 64) o[(size_t)t*S_*D_ + h*64 + tid] = vbase[tid];
  __syncthreads();

  const int lane = tid & 63, wid = tid >> 6;
  const int lr = lane & 15, lk = (lane >> 4) * 8;
  const int gg = (lane >> 4) * 4;
  const f32x4 fzero = {0.f,0.f,0.f,0.f};

  // pad cols of Pl are written once (never overwritten by P stores, cols < 272)
  #pragma unroll
  for (int r = 0; r < 4; ++r) Pl[wid][gg + r][272 + lr] = 0;

  for (int qt = wid; qt < 17; qt += 4) {
    int qrow = qt*16 + lr; if (qrow >= S_) qrow = 0;
    const short* qbase = qkv + (size_t)(t*S_ + qrow)*3072 + h*64;
    s16x8 qf0 = *(const s16x8*)(qbase + lk);
    s16x8 qf1 = *(const s16x8*)(qbase + 32 + lk);

    f32x4 lg[17];
    #pragma unroll
    for (int nt = 0; nt < 17; ++nt) lg[nt] = fzero;
    __builtin_amdgcn_s_setprio(1);
    #pragma unroll
    for (int nt = 0; nt < 17; ++nt) {
      int krow = nt*16 + lr; if (krow >= S_) krow = S_ - 1;
      s16x8 kf0 = *(const s16x8*)(kbase + (size_t)krow*3072 + lk);
      s16x8 kf1 = *(const s16x8*)(kbase + (size_t)krow*3072 + 32 + lk);
      lg[nt] = __builtin_amdgcn_mfma_f32_16x16x32_bf16(qf0, kf0, lg[nt], 0, 0, 0);
      lg[nt] = __builtin_amdgcn_mfma_f32_16x16x32_bf16(qf1, kf1, lg[nt], 0, 0, 0);
    }
    __builtin_amdgcn_s_setprio(0);
    float is_[4];
    #pragma unroll
    for (int r = 0; r < 4; ++r) {
      float sum = 0.f;
      #pragma unroll
      for (int nt = 0; nt < 17; ++nt) {
        float v = softcap(lg[nt][r] * 0.125f);
        float pe = (nt*16 + lr >= S_) ? 0.f : __expf(v);
        lg[nt][r] = pe;
        sum += pe;
      }
      sum += __shfl_xor(sum, 1);
      sum += __shfl_xor(sum, 2);
      sum += __shfl_xor(sum, 4);
      sum += __shfl_xor(sum, 8);
      is_[r] = 1.f / sum;
      #pragma unroll
      for (int nt = 0; nt < 17; ++nt) Pl[wid][gg + r][nt*16 + lr] = f2bf(lg[nt][r]);
    }
    f32x4 oacc[4];
    #pragma unroll
    for (int ni = 0; ni < 4; ++ni) oacc[ni] = fzero;
    __builtin_amdgcn_s_setprio(1);
    #pragma unroll
    for (int ks = 0; ks < 9; ++ks) {
      s16x8 pf = *(const s16x8*)&Pl[wid][lr][ks*32 + lk];
      #pragma unroll
      for (int ni = 0; ni < 4; ++ni) {
        s16x8 vf = *(const s16x8*)&Vt[ni*16 + lr][ks*32 + lk];
        oacc[ni] = __builtin_amdgcn_mfma_f32_16x16x32_bf16(pf, vf, oacc[ni], 0, 0, 0);
      }
    }
    __builtin_amdgcn_s_setprio(0);
    #pragma unroll
    for (int ni = 0; ni < 4; ++ni)
      #pragma unroll
      for (int r = 0; r < 4; ++r) {
        int q = qt*16 + gg + r;
        if (q < S_ && q != 0) o[(size_t)(t*S_ + q)*D_ + h*64 + ni*16 + lr] = f2bf(oacc[ni][r] * is_[r]);
      }
  }
}

// ---------------------------------------------------------------- temporal attention
__global__ __launch_bounds__(256)
void attn_temporal_k(const short* __restrict__ qkv, short* __restrict__ o)
{
  __shared__ float Ql[4][16][68];
  __shared__ float Kl[4][16][68];
  __shared__ float Vl[4][16][68];
  __shared__ float Pl2[4][16][17];
  const int tid = threadIdx.x, lane = tid & 63, wid = tid >> 6;
  const int gw = blockIdx.x*4 + wid;
  const int s = gw >> 4, h = gw & 15;
  const int tt = lane >> 2, dp = (lane & 3) * 16;
  const short* base = qkv + (size_t)(tt*S_ + s)*3072 + h*64 + dp;
  #pragma unroll
  for (int part = 0; part < 3; ++part) {
    const short* bp = base + part*1024;
    s16x8 v0 = *(const s16x8*)(bp);
    s16x8 v1 = *(const s16x8*)(bp + 8);
    float* dst = (part == 0) ? &Ql[wid][tt][dp] : (part == 1) ? &Kl[wid][tt][dp] : &Vl[wid][tt][dp];
    #pragma unroll
    for (int j = 0; j < 8; ++j) { dst[j] = bf2f(v0[j]); dst[8 + j] = bf2f(v1[j]); }
  }
  __syncthreads();
  const int qr = lane >> 2;
  float qv[64];
  #pragma unroll
  for (int j = 0; j < 64; ++j) qv[j] = Ql[wid][qr][j];
  float pvals[4];
  #pragma unroll
  for (int i = 0; i < 4; ++i) {
    int kt = (lane & 3) + i*4;
    float d = 0.f;
    #pragma unroll
    for (int j = 0; j < 64; ++j) d += qv[j] * Kl[wid][kt][j];
    d *= 0.125f;
    d = softcap(d);                       // bounded to [-50,50] -> exp safe w/o max
    bool keep = (kt <= qr) && (kt + 9 >= qr);
    pvals[i] = keep ? __expf(d) : 0.f;
  }
  float sum = pvals[0] + pvals[1] + pvals[2] + pvals[3];
  sum += __shfl_xor(sum, 1);
  sum += __shfl_xor(sum, 2);
  float is = 1.f / sum;
  #pragma unroll
  for (int i = 0; i < 4; ++i) Pl2[wid][qr][(lane & 3) + i*4] = pvals[i] * is;
  __syncthreads();
  float acc[16];
  #pragma unroll
  for (int j = 0; j < 16; ++j) acc[j] = 0.f;
  #pragma unroll
  for (int kt = 0; kt < 16; ++kt) {
    float pv = Pl2[wid][qr][kt];
    #pragma unroll
    for (int j = 0; j < 16; ++j) acc[j] += pv * Vl[wid][kt][dp + j];
  }
  short* op = o + (size_t)(qr*S_ + s)*D_ + h*64 + dp;
  #pragma unroll
  for (int j = 0; j < 16; ++j) op[j] = f2bf(acc[j]);
}

// ---------------------------------------------------------------- conversions / prologue
struct CvtJobs {
  const float* src[10];
  short* dst[10];
  int end[10];
  int njobs;
};

__global__ void cvt_multi_k(CvtJobs jobs)
{
  int q = blockIdx.x*256 + threadIdx.x;
  int j = 0;
  while (j < jobs.njobs && q >= jobs.end[j]) ++j;
  if (j >= jobs.njobs) return;
  int base = (j == 0) ? 0 : jobs.end[j-1];
  size_t idx = (size_t)(q - base);
  float4 v = *(const float4*)(jobs.src[j] + idx*4);
  s16x4 ov; ov[0]=f2bf(v.x); ov[1]=f2bf(v.y); ov[2]=f2bf(v.z); ov[3]=f2bf(v.w);
  *(s16x4*)(jobs.dst[j] + idx*4) = ov;
}

__global__ void cvt_f32_bf16_k(const float* __restrict__ in, short* __restrict__ out, int n4)
{
  int i = blockIdx.x*256 + threadIdx.x;
  if (i >= n4) return;
  float4 v = *(const float4*)(in + (size_t)i*4);
  s16x4 ov; ov[0]=f2bf(v.x); ov[1]=f2bf(v.y); ov[2]=f2bf(v.z); ov[3]=f2bf(v.w);
  *(s16x4*)(out + (size_t)i*4) = ov;
}

// w12: permute rows so gate/val interleave in 16-blocks within 32 (fused swiglu epilogue)
__global__ void cvt_w12_k(const float* __restrict__ in, short* __restrict__ out)
{
  int pb = blockIdx.x;             // 8 layers * 8192 rows
  int l = pb >> 13, pr = pb & 8191;
  int c = pr >> 5, q = pr & 31;
  int orig = (q < 16) ? c*16 + q : DH_ + c*16 + (q - 16);
  const float* ip = in + ((size_t)l*8192 + orig)*1024 + threadIdx.x*4;
  short* op = out + ((size_t)l*8192 + pr)*1024 + threadIdx.x*4;
  float4 v = *(const float4*)ip;
  s16x4 ov; ov[0]=f2bf(v.x); ov[1]=f2bf(v.y); ov[2]=f2bf(v.z); ov[3]=f2bf(v.w);
  *(s16x4*)op = ov;
}

__global__ void timestep_embed_k(const float* __restrict__ sig, float* __restrict__ emb)
{
  int tid = threadIdx.x;
  int n = tid >> 4;
  int j0 = (tid & 15) * 16;
  float tv = sig[n];
  for (int j = j0; j < j0 + 16; ++j) {
    int half = j & 127;
    float freq = expf(-9.210340371976184f * (float)half / 128.f);
    float a = tv * freq;
    emb[n*256 + j] = (j < 128) ? cosf(a) : sinf(a);
  }
}

__global__ void noise_mlp1_k(const float* __restrict__ emb, const float* __restrict__ w1,
                             const float* __restrict__ b1, float* __restrict__ hid)
{
  const int o = blockIdx.x*256 + threadIdx.x;
  const int n = o >> 10, e = o & 1023;
  const float4* er = (const float4*)(emb + n*256);
  const float4* wr = (const float4*)(w1 + (size_t)e*256);
  float s = b1[e];
  for (int k = 0; k < 64; ++k) { float4 a = er[k]; float4 b = wr[k]; s += a.x*b.x + a.y*b.y + a.z*b.z + a.w*b.w; }
  hid[o] = s / (1.f + __expf(-s));
}

__global__ void noise_mlp2_k(const float* __restrict__ hid, const float* __restrict__ w2,
                             const float* __restrict__ b2, float* __restrict__ sg)
{
  const int o = blockIdx.x*256 + threadIdx.x;
  const int n = o >> 10, e = o & 1023;
  const float4* hr = (const float4*)(hid + n*1024);
  const float4* wr = (const float4*)(w2 + (size_t)e*1024);
  float s = b2[e];
  for (int k = 0; k < 256; ++k) { float4 a = hr[k]; float4 b = wr[k]; s += a.x*b.x + a.y*b.y + a.z*b.z + a.w*b.w; }
  sg[o] = s;
}

__global__ void act_embed_k(const float* __restrict__ actions, const float* __restrict__ base,
                            const float* __restrict__ apw, const float* __restrict__ apb,
                            float* __restrict__ ar)
{
  const int o = blockIdx.x*256 + threadIdx.x;
  const int n = o >> 10, e = o & 1023;
  float s = base[e] + apb[e];
  #pragma unroll
  for (int j = 0; j < 8; ++j) s += actions[n*8 + j] * apw[(size_t)e*8 + j];
  ar[o] = s;
}

__global__ void fill6_k(const float* __restrict__ sig, const float* __restrict__ act,
                        const float* __restrict__ reg, float* __restrict__ x)
{
  const int b = blockIdx.x;            // 16*6
  const int t = b / 6, s = b % 6;
  const int d = threadIdx.x * 4;
  float4 v;
  if (s == 0)      v = *(const float4*)(sig + t*D_ + d);
  else if (s == 1) v = *(const float4*)(act + t*D_ + d);
  else             v = *(const float4*)(reg + (s-2)*D_ + d);
  *(float4*)(x + (size_t)(t*S_ + s)*D_ + d) = v;
}

// ---------------------------------------------------------------- host
extern "C" void kernel_launch(void* const* d_in, const int* in_sizes, int n_in,
                              void* d_out, int out_size, void* d_ws, size_t ws_size,
                              hipStream_t stream)
{
  (void)in_sizes; (void)n_in; (void)out_size;
  const float* noisy   = (const float*)d_in[0];
  const float* sig_lv  = (const float*)d_in[1];
  const float* actions = (const float*)d_in[2];
  const float* in_proj = (const float*)d_in[3];
  const float* nw1     = (const float*)d_in[4];
  const float* nb1     = (const float*)d_in[5];
  const float* nw2     = (const float*)d_in[6];
  const float* nb2     = (const float*)d_in[7];
  const float* base_ae = (const float*)d_in[8];
  const float* apw     = (const float*)d_in[9];
  const float* apb     = (const float*)d_in[10];
  const float* regtok  = (const float*)d_in[11];
  const float* ln1w    = (const float*)d_in[12];
  const float* s_wqkv  = (const float*)d_in[13];
  const float* s_wo    = (const float*)d_in[14];
  const float* s_qg    = (const float*)d_in[15];
  const float* s_kg    = (const float*)d_in[16];
  const float* lntw    = (const float*)d_in[17];
  const float* t_wqkv  = (const float*)d_in[18];
  const float* t_wo    = (const float*)d_in[19];
  const float* t_qg    = (const float*)d_in[20];
  const float* t_kg    = (const float*)d_in[21];
  const float* ln2w    = (const float*)d_in[22];
  const float* w12     = (const float*)d_in[23];
  const float* w3      = (const float*)d_in[24];
  const float* fnw     = (const float*)d_in[25];
  const float* outw    = (const float*)d_in[26];
  const float* outb    = (const float*)d_in[27];

  char* p = (char*)d_ws;
  auto take = [&](size_t n) { char* r = p; p += n; return r; };
  float* x   = (float*)take((size_t)NTOK*D_*4);
  short* hb  = (short*)take((size_t)NTOK*D_*2);
  short* qkv = (short*)take((size_t)NTOK*3072*2);
  short* ob  = (short*)take((size_t)NTOK*D_*2);
  short* mb  = qkv;                               // spans qkv+ob exactly (NTOK*4096*2)
  short* nlb = (short*)take((size_t)4096*INDIM_*2);
  float* emb = (float*)take(16*256*4);
  float* hid = (float*)take(16*1024*4);
  float* sgb = (float*)take(16*1024*4);
  float* acr = (float*)take(16*1024*4);
  float* csS = (float*)take(S_*32*4);
  float* snS = (float*)take(S_*32*4);
  float* csT = (float*)take(16*32*4);
  float* snT = (float*)take(16*32*4);
  short* wqkv_s_bf = (short*)take((size_t)8*3*D_*D_*2);
  short* wo_s_bf   = (short*)take((size_t)8*D_*D_*2);
  short* wqkv_t_bf = (short*)take((size_t)2*3*D_*D_*2);
  short* wo_t_bf   = (short*)take((size_t)2*D_*D_*2);
  short* w12_bf    = (short*)take((size_t)8*2*DH_*D_*2);
  short* w3_bf     = (short*)take((size_t)8*D_*DH_*2);
  short* inp_bf    = (short*)take((size_t)D_*INDIM_*2);
  short* outw_bf   = (short*)take((size_t)INDIM_*D_*2);
  const size_t full_need = (size_t)(p - (char*)d_ws);
  const bool wb = ws_size >= full_need;

  if (wb) {
    CvtJobs jobs;
    int acc_q = 0, nj = 0;
    auto add = [&](const float* s, short* d, size_t elems) {
      jobs.src[nj] = s; jobs.dst[nj] = d;
      acc_q += (int)(elems / 4); jobs.end[nj] = acc_q; ++nj;
    };
    add(s_wqkv, wqkv_s_bf, (size_t)8*3*D_*D_);
    add(s_wo,   wo_s_bf,   (size_t)8*D_*D_);
    add(t_wqkv,                     wqkv_t_bf,                   (size_t)3*D_*D_);
    add(t_wqkv + (size_t)4*3*D_*D_, wqkv_t_bf + (size_t)3*D_*D_, (size_t)3*D_*D_);
    add(t_wo,                       wo_t_bf,                     (size_t)D_*D_);
    add(t_wo + (size_t)4*D_*D_,     wo_t_bf + (size_t)D_*D_,     (size_t)D_*D_);
    add(w3,   w3_bf,   (size_t)8*D_*DH_);
    add(in_proj, inp_bf, (size_t)D_*INDIM_);
    add(outw,    outw_bf,(size_t)INDIM_*D_);
    add(noisy,   nlb,    (size_t)4096*INDIM_);
    jobs.njobs = nj;
    cvt_multi_k<<<(acc_q + 255)/256, 256, 0, stream>>>(jobs);
    cvt_w12_k<<<65536, 256, 0, stream>>>(w12, w12_bf);
  } else {
    cvt_f32_bf16_k<<<3072, 256, 0, stream>>>(noisy, nlb, 4096*INDIM_/4);
  }
  rope_tab_k<<<33, 256, 0, stream>>>(csS, snS, S_);
  rope_tab_k<<<2,  256, 0, stream>>>(csT, snT, 16);

  // prologue
  timestep_embed_k<<<1, 256, 0, stream>>>(sig_lv, emb);
  noise_mlp1_k<<<64, 256, 0, stream>>>(emb, nw1, nb1, hid);
  noise_mlp2_k<<<64, 256, 0, stream>>>(hid, nw2, nb2, sgb);
  act_embed_k<<<64, 256, 0, stream>>>(actions, base_ae, apw, apb, acr);
  if (wb) gemm2<1,0,0,0,1,0,0,1><<<dim3(16,64), 256, 0, stream>>>(nlb, inp_bf,  nullptr, x, 4096, D_, INDIM_, nullptr, nullptr, nullptr, nullptr);
  else    gemm2<1,0,0,0,0,0,0,1><<<dim3(16,64), 256, 0, stream>>>(nlb, in_proj, nullptr, x, 4096, D_, INDIM_, nullptr, nullptr, nullptr, nullptr);
  fill6_k<<<96, 256, 0, stream>>>(sgb, acr, regtok, x);

  for (int l = 0; l < 8; ++l) {
    rmsnorm_k<0><<<NTOK/4, 256, 0, stream>>>(x, ln1w + l*D_, hb);
    if (wb) gemm2<0,0,0,1,1,0,1,0><<<dim3(24,33), 256, 0, stream>>>(hb, wqkv_s_bf + (size_t)l*3*D_*D_, nullptr, qkv, NTOK, 3*D_, D_, s_qg + l*HD_, s_kg + l*HD_, csS, snS);
    else    gemm2<0,0,0,1,0,0,1,0><<<dim3(24,33), 256, 0, stream>>>(hb, s_wqkv   + (size_t)l*3*D_*D_, nullptr, qkv, NTOK, 3*D_, D_, s_qg + l*HD_, s_kg + l*HD_, csS, snS);
    attn_spatial_k<<<256, 256, 0, stream>>>(qkv, ob);
    if (wb) gemm2<1,1,0,0,1,0,0,0><<<dim3(16,66), 256, 0, stream>>>(ob, wo_s_bf + (size_t)l*D_*D_, nullptr, x, NTOK, D_, D_, nullptr, nullptr, nullptr, nullptr);
    else    gemm2<1,1,0,0,0,0,0,0><<<dim3(16,66), 256, 0, stream>>>(ob, s_wo    + (size_t)l*D_*D_, nullptr, x, NTOK, D_, D_, nullptr, nullptr, nullptr, nullptr);
    if (l % 4 == 0) {
      const int ls = l / 4;
      rmsnorm_k<0><<<NTOK/4, 256, 0, stream>>>(x, lntw + l*D_, hb);
      if (wb) gemm2<0,0,0,1,1,0,2,0><<<dim3(24,33), 256, 0, stream>>>(hb, wqkv_t_bf + (size_t)ls*3*D_*D_, nullptr, qkv, NTOK, 3*D_, D_, t_qg + l*HD_, t_kg + l*HD_, csT, snT);
      else    gemm2<0,0,0,1,0,0,2,0><<<dim3(24,33), 256, 0, stream>>>(hb, t_wqkv    + (size_t)l*3*D_*D_,  nullptr, qkv, NTOK, 3*D_, D_, t_qg + l*HD_, t_kg + l*HD_, csT, snT);
      attn_temporal_k<<<1048, 256, 0, stream>>>(qkv, ob);
      if (wb) gemm2<1,1,0,0,1,0,0,0><<<dim3(16,66), 256, 0, stream>>>(ob, wo_t_bf + (size_t)ls*D_*D_, nullptr, x, NTOK, D_, D_, nullptr, nullptr, nullptr, nullptr);
      else    gemm2<1,1,0,0,0,0,0,0><<<dim3(16,66), 256, 0, stream>>>(ob, t_wo    + (size_t)l*D_*D_,  nullptr, x, NTOK, D_, D_, nullptr, nullptr, nullptr, nullptr);
    }
    rmsnorm_k<0><<<NTOK/4, 256, 0, stream>>>(x, ln2w + l*D_, hb);
    if (wb) gemm2<0,0,0,2,1,0,0,0><<<dim3(64,33), 256, 0, stream>>>(hb, w12_bf + (size_t)l*2*DH_*D_, nullptr, mb, NTOK, 2*DH_, D_, nullptr, nullptr, nullptr, nullptr);
    else    gemm2<0,0,0,2,0,1,0,0><<<dim3(64,33), 256, 0, stream>>>(hb, w12    + (size_t)l*2*DH_*D_, nullptr, mb, NTOK, 2*DH_, D_, nullptr, nullptr, nullptr, nullptr);
    if (wb) gemm2<1,1,0,0,1,0,0,0><<<dim3(16,66), 256, 0, stream>>>(mb, w3_bf + (size_t)l*D_*DH_, nullptr, x, NTOK, D_, DH_, nullptr, nullptr, nullptr, nullptr);
    else    gemm2<1,1,0,0,0,0,0,0><<<dim3(16,66), 256, 0, stream>>>(mb, w3    + (size_t)l*D_*DH_, nullptr, x, NTOK, D_, DH_, nullptr, nullptr, nullptr, nullptr);
  }
  rmsnorm_k<1><<<1024, 256, 0, stream>>>(x, fnw, hb);
  if (wb) gemm2<1,0,1,0,1,0,0,0><<<dim3(12,64), 256, 0, stream>>>(hb, outw_bf, outb, (float*)d_out, 4096, INDIM_, D_, nullptr, nullptr, nullptr, nullptr);
  else    gemm2<1,0,1,0,0,0,0,0><<<dim3(12,64), 256, 0, stream>>>(hb, outw,    outb, (float*)d_out, 4096, INDIM_, D_, nullptr, nullptr, nullptr, nullptr);
}

// Round 15
// 2755.427 us; speedup vs baseline: 1.0768x; 1.0032x over previous
//
#include <hip/hip_runtime.h>
#include <hip/hip_bf16.h>
#include <math.h>

#define T_ 16
#define S_ 262
#define D_ 1024
#define H_ 16
#define HD_ 64
#define DH_ 4096
#define NTOK (T_*S_)     // 4192
#define LTOK_ 256
#define INDIM_ 768

typedef __attribute__((ext_vector_type(4))) float f32x4;
typedef __attribute__((ext_vector_type(8))) short s16x8;
typedef __attribute__((ext_vector_type(4))) short s16x4;

__device__ __forceinline__ short f2bf(float f) {
  union { float f; unsigned u; } v; v.f = f;
  unsigned r = v.u + 0x7fffu + ((v.u >> 16) & 1u);
  return (short)(r >> 16);
}
__device__ __forceinline__ float bf2f(short h) {
  union { unsigned u; float f; } v; v.u = ((unsigned)(unsigned short)h) << 16;
  return v.f;
}
__device__ __forceinline__ float softcap(float x) {
  float z = __expf(x * (2.0f / 50.0f));
  return 50.0f * (z - 1.0f) / (z + 1.0f);
}
// exp(softcap(logit*0.125)) folded: z = exp(logit*0.005); p = e^50 * exp(-100/(z+1)).
// Bounded by e^50 (same as R14's verified unnormalized-P range); e^50 cancels in
// normalization; underflow corner (w<=-88 -> p=0) is < 1e-38 of row sum.
#define EXP50_ 5.184705528587072e21f
__device__ __forceinline__ float exp_softcap(float logit) {
  float z = __expf(logit * 0.005f);
  return EXP50_ * __expf(-100.0f / (z + 1.0f));
}
__device__ __forceinline__ void gload16(const void* g, void* l) {
  __builtin_amdgcn_global_load_lds((const __attribute__((address_space(1))) void*)g,
                                   (__attribute__((address_space(3))) void*)l, 16, 0, 0);
}

// ---------------------------------------------------------------- GEMM
// C[M,N] = A_bf16[M,K] * W[N,K]^T
// SMALL: 0 -> 128x128 tile; 1 -> 64x64 tile.
//   TILE-SIZE LESSON (R5-R10 A/B): skinny GEMMs (N<=1024, M~4224) MUST use 64²
//   (occupancy/TLP-bound: 128² -> 1 block/CU ~600us loss; BK=128 -> 5 blocks/CU
//   ~150us loss). Big GEMMs (qkv N=3072, w12 N=8192) use 128². BK=64 everywhere.
//   XCD swizzle: neutral (R7). 256² coarse 2-phase: negative (R9).
// OUT: 0 f32, 1 bf16, 2 fused-swiglu bf16 (out cols N/2)   RESID: 1 -> f32 +=
// PREP: 1 spatial qk rms+rope, 2 temporal (only with SMALL=0)
// ROWMAP: out row -> (row>>8)*S_+6+(row&255)
template<int SMALL, int RESID, int BIAS, int OUT, int WB, int PERM, int PREP, int ROWMAP>
__global__ __launch_bounds__(256)
void gemm2(const short* __restrict__ A, const void* __restrict__ Wv,
           const float* __restrict__ bias, void* __restrict__ Cv,
           int M, int N, int K,
           const float* __restrict__ qg, const float* __restrict__ kg,
           const float* __restrict__ ctab, const float* __restrict__ stab)
{
  constexpr int BM   = SMALL ? 64 : 128;
  constexpr int MI   = SMALL ? 2 : 4;     // 16x16 frags per wave per dim
  constexpr int WR   = SMALL ? 32 : 64;   // per-wave tile
  constexpr int NSTG = SMALL ? 2 : 4;     // staging iters (8 rows/wave each)
  __shared__ __align__(16) short As[BM*64];
  __shared__ __align__(16) short Bs[BM*64];
  const int tid = threadIdx.x;
  const int m0 = blockIdx.y * BM, n0 = blockIdx.x * BM;
  const int lane = tid & 63, wid = tid >> 6;
  const int wr = (wid >> 1) * WR, wc = (wid & 1) * WR;
  const int lr = lane & 15, lk = (lane >> 4) * 8;
  const short* Wb = (const short*)Wv;
  const float* Wf = (const float*)Wv;

  const f32x4 fzero = {0.f, 0.f, 0.f, 0.f};
  f32x4 acc[MI][MI];
  #pragma unroll
  for (int i = 0; i < MI; ++i)
    #pragma unroll
    for (int j = 0; j < MI; ++j) acc[i][j] = fzero;

  for (int k0 = 0; k0 < K; k0 += 64) {
    #pragma unroll
    for (int i = 0; i < NSTG; ++i) {         // A tile, swizzled global source
      int row = wid*(NSTG*8) + i*8 + (lane >> 3);
      int gm = m0 + row; if (gm >= M) gm = M - 1;
      int gc = (((lane & 7) ^ (row & 7)) << 3);
      gload16(A + (size_t)gm*K + k0 + gc, &As[(wid*(NSTG*8) + i*8)*64]);
    }
    if constexpr (WB) {
      #pragma unroll
      for (int i = 0; i < NSTG; ++i) {
        int row = wid*(NSTG*8) + i*8 + (lane >> 3);
        int gc = (((lane & 7) ^ (row & 7)) << 3);
        gload16(Wb + (size_t)(n0 + row)*K + k0 + gc, &Bs[(wid*(NSTG*8) + i*8)*64]);
      }
    } else {
      #pragma unroll
      for (int i = 0; i < NSTG; ++i) {       // fallback: reg-stage f32 -> bf16
        int slot = tid + 256*i;
        int row = slot >> 3, c8 = (slot & 7) << 3;
        int gr = n0 + row;
        if (PERM) { int c = gr >> 5, q = gr & 31; gr = (q < 16) ? c*16 + q : DH_ + c*16 + (q - 16); }
        const float* wp = Wf + (size_t)gr*K + k0 + c8;
        float4 w0 = *(const float4*)wp, w1 = *(const float4*)(wp + 4);
        s16x8 b;
        b[0]=f2bf(w0.x); b[1]=f2bf(w0.y); b[2]=f2bf(w0.z); b[3]=f2bf(w0.w);
        b[4]=f2bf(w1.x); b[5]=f2bf(w1.y); b[6]=f2bf(w1.z); b[7]=f2bf(w1.w);
        *(s16x8*)&Bs[row*64 + (c8 ^ ((row & 7) << 3))] = b;
      }
    }
    __syncthreads();
    #pragma unroll
    for (int kh = 0; kh < 2; ++kh) {
      const int col0 = kh*32 + lk;
      s16x8 af[MI], bfr[MI];
      #pragma unroll
      for (int mi = 0; mi < MI; ++mi) {
        int row = wr + mi*16 + lr;
        af[mi] = *(const s16x8*)&As[row*64 + (col0 ^ ((row & 7) << 3))];
      }
      #pragma unroll
      for (int ni = 0; ni < MI; ++ni) {
        int row = wc + ni*16 + lr;
        bfr[ni] = *(const s16x8*)&Bs[row*64 + (col0 ^ ((row & 7) << 3))];
      }
      #pragma unroll
      for (int mi = 0; mi < MI; ++mi)
        #pragma unroll
        for (int ni = 0; ni < MI; ++ni)
          acc[mi][ni] = __builtin_amdgcn_mfma_f32_16x16x32_bf16(af[mi], bfr[ni], acc[mi][ni], 0, 0, 0);
    }
    __syncthreads();
  }
  const int gg = (lane >> 4) * 4;
  if constexpr (OUT == 2) {
    #pragma unroll
    for (int mi = 0; mi < MI; ++mi)
      #pragma unroll
      for (int np = 0; np < MI/2; ++np) {
        const int ni = np*2;
        const int ocol = ((n0 + wc + ni*16) >> 5) * 16 + lr;
        #pragma unroll
        for (int r = 0; r < 4; ++r) {
          int row = m0 + wr + mi*16 + gg + r;
          if (row < M) {
            float g = acc[mi][ni][r], v = acc[mi][ni+1][r];
            float sl = g / (1.f + __expf(-g));
            ((short*)Cv)[(size_t)row * (N >> 1) + ocol] = f2bf(sl * v);
          }
        }
      }
  } else if constexpr (PREP != 0) {
    const int colsec = n0 + wc;              // wave-uniform
    const bool isv = (colsec >= 2048);
    const float* gp = (colsec < 1024) ? qg : kg;
    float gv[MI];
    if (!isv) {
      #pragma unroll
      for (int ni = 0; ni < MI; ++ni) gv[ni] = gp[ni*16 + lr];
    }
    #pragma unroll
    for (int mi = 0; mi < MI; ++mi) {
      #pragma unroll
      for (int r = 0; r < 4; ++r) {
        int row = m0 + wr + mi*16 + gg + r;
        int rowc = row < M ? row : M - 1;
        float vv[MI];
        #pragma unroll
        for (int ni = 0; ni < MI; ++ni) vv[ni] = acc[mi][ni][r];
        if (!isv) {
          float ss = vv[0]*vv[0] + vv[1]*vv[1] + vv[2]*vv[2] + vv[3]*vv[3];
          ss += __shfl_xor(ss, 1);
          ss += __shfl_xor(ss, 2);
          ss += __shfl_xor(ss, 4);
          ss += __shfl_xor(ss, 8);
          float sc = rsqrtf(ss * (1.f/64.f) + 1e-6f);
          int pos = (PREP == 1) ? (rowc % S_) : (rowc / S_);
          float c0 = ctab[pos*32 + lr],      s0 = stab[pos*32 + lr];
          float c1 = ctab[pos*32 + 16 + lr], s1 = stab[pos*32 + 16 + lr];
          float a0 = vv[0]*sc*gv[0], a1 = vv[1]*sc*gv[1];
          float a2 = vv[2]*sc*gv[2], a3 = vv[3]*sc*gv[3];
          vv[0] = a0*c0 - a2*s0;
          vv[1] = a1*c1 - a3*s1;
          vv[2] = a0*s0 + a2*c0;
          vv[3] = a1*s1 + a3*c1;
        }
        if (row < M) {
          #pragma unroll
          for (int ni = 0; ni < MI; ++ni)
            ((short*)Cv)[(size_t)row * N + n0 + wc + ni*16 + lr] = f2bf(vv[ni]);
        }
      }
    }
  } else {
    #pragma unroll
    for (int mi = 0; mi < MI; ++mi)
      #pragma unroll
      for (int ni = 0; ni < MI; ++ni) {
        int col = n0 + wc + ni*16 + lr;
        #pragma unroll
        for (int r = 0; r < 4; ++r) {
          int row = m0 + wr + mi*16 + gg + r;
          if (row < M) {
            float v = acc[mi][ni][r];
            if (BIAS) v += bias[col];
            size_t orow = ROWMAP ? (size_t)((row >> 8) * S_ + 6 + (row & 255)) : (size_t)row;
            size_t idx = orow * N + col;
            if (RESID == 1)       ((float*)Cv)[idx] += v;
            else if (OUT == 1)    ((short*)Cv)[idx]  = f2bf(v);
            else                  ((float*)Cv)[idx]  = v;
          }
        }
      }
  }
}

// ---------------------------------------------------------------- RMSNorm (wave per row)
template<int FINAL>
__global__ __launch_bounds__(256)
void rmsnorm_k(const float* __restrict__ x, const float* __restrict__ w, short* __restrict__ h)
{
  const int lane = threadIdx.x & 63;
  const int row = blockIdx.x*4 + (threadIdx.x >> 6);
  const int xrow = FINAL ? ((row >> 8) * S_ + 6 + (row & 255)) : row;
  const float* xp = x + (size_t)xrow*D_;
  float4 v[4];
  #pragma unroll
  for (int j = 0; j < 4; ++j) v[j] = *(const float4*)(xp + j*256 + lane*4);
  float ss = 0.f;
  #pragma unroll
  for (int j = 0; j < 4; ++j) ss += v[j].x*v[j].x + v[j].y*v[j].y + v[j].z*v[j].z + v[j].w*v[j].w;
  #pragma unroll
  for (int m = 1; m < 64; m <<= 1) ss += __shfl_xor(ss, m);
  const float sc = rsqrtf(ss * (1.f/1024.f) + 1e-6f);
  #pragma unroll
  for (int j = 0; j < 4; ++j) {
    float4 wv = *(const float4*)(w + j*256 + lane*4);
    s16x4 hv;
    hv[0] = f2bf(v[j].x*sc*wv.x); hv[1] = f2bf(v[j].y*sc*wv.y);
    hv[2] = f2bf(v[j].z*sc*wv.z); hv[3] = f2bf(v[j].w*sc*wv.w);
    *(s16x4*)(h + (size_t)row*D_ + j*256 + lane*4) = hv;
  }
}

// ---------------------------------------------------------------- rope tables
__global__ void rope_tab_k(float* __restrict__ ct, float* __restrict__ st, int npos)
{
  int i = blockIdx.x*256 + threadIdx.x;
  if (i >= npos*32) return;
  int pos = i >> 5, fi = i & 31;
  float ang = (float)pos * expf((float)fi * (-9.210340371976184f/32.f));
  float s, c; sincosf(ang, &s, &c);
  ct[i] = c; st[i] = s;
}

// ---------------------------------------------------------------- spatial attention
// R13: no max-subtraction (softcap bounds logits). R14: unnormalized P, 1/sum in
// epilogue. R15: exp(softcap) folded to e^50*exp(-100/(z+1)) (same e^50 bound).
__global__ __launch_bounds__(256)
void attn_spatial_k(const short* __restrict__ qkv, short* __restrict__ o)
{
  __shared__ __align__(16) short Vt[64][296];
  __shared__ __align__(16) short Pl[4][16][296];
  const int tid = threadIdx.x;
  const int b = blockIdx.x;          // T*H = 256
  const int t = b >> 4, h = b & 15;
  const short* kbase = qkv + (size_t)t*S_*3072 + 1024 + h*64;
  const short* vbase = kbase + 1024;
  const s16x8 zv = {0,0,0,0,0,0,0,0};
  #pragma unroll
  for (int i = 0; i < 9; ++i) {
    int slot = tid + 256*i;
    if (slot < 2176) {
      int row = slot >> 3, c8 = (slot & 7) * 8;
      s16x8 v = zv;
      if (row < S_) v = *(const s16x8*)(vbase + (size_t)row*3072 + c8);
      #pragma unroll
      for (int j = 0; j < 8; ++j) Vt[c8 + j][row] = v[j];
    }
  }
  #pragma unroll
  for (int i = 0; i < 6; ++i) {
    int slot = tid + 256*i;
    Vt[slot / 24][272 + (slot % 24)] = 0;
  }
  if (tid < 64) o[(size_t)t*S_*D_ + h*64 + tid] = vbase[tid];
  __syncthreads();

  const int lane = tid & 63, wid = tid >> 6;
  const int lr = lane & 15, lk = (lane >> 4) * 8;
  const int gg = (lane >> 4) * 4;
  const f32x4 fzero = {0.f,0.f,0.f,0.f};

  // pad cols of Pl are written once (never overwritten by P stores, cols < 272)
  #pragma unroll
  for (int r = 0; r < 4; ++r) Pl[wid][gg + r][272 + lr] = 0;

  for (int qt = wid; qt < 17; qt += 4) {
    int qrow = qt*16 + lr; if (qrow >= S_) qrow = 0;
    const short* qbase = qkv + (size_t)(t*S_ + qrow)*3072 + h*64;
    s16x8 qf0 = *(const s16x8*)(qbase + lk);
    s16x8 qf1 = *(const s16x8*)(qbase + 32 + lk);

    f32x4 lg[17];
    #pragma unroll
    for (int nt = 0; nt < 17; ++nt) lg[nt] = fzero;
    __builtin_amdgcn_s_setprio(1);
    #pragma unroll
    for (int nt = 0; nt < 17; ++nt) {
      int krow = nt*16 + lr; if (krow >= S_) krow = S_ - 1;
      s16x8 kf0 = *(const s16x8*)(kbase + (size_t)krow*3072 + lk);
      s16x8 kf1 = *(const s16x8*)(kbase + (size_t)krow*3072 + 32 + lk);
      lg[nt] = __builtin_amdgcn_mfma_f32_16x16x32_bf16(qf0, kf0, lg[nt], 0, 0, 0);
      lg[nt] = __builtin_amdgcn_mfma_f32_16x16x32_bf16(qf1, kf1, lg[nt], 0, 0, 0);
    }
    __builtin_amdgcn_s_setprio(0);
    float is_[4];
    #pragma unroll
    for (int r = 0; r < 4; ++r) {
      float sum = 0.f;
      #pragma unroll
      for (int nt = 0; nt < 17; ++nt) {
        float pe = (nt*16 + lr >= S_) ? 0.f : exp_softcap(lg[nt][r]);
        lg[nt][r] = pe;
        sum += pe;
      }
      sum += __shfl_xor(sum, 1);
      sum += __shfl_xor(sum, 2);
      sum += __shfl_xor(sum, 4);
      sum += __shfl_xor(sum, 8);
      is_[r] = 1.f / sum;
      #pragma unroll
      for (int nt = 0; nt < 17; ++nt) Pl[wid][gg + r][nt*16 + lr] = f2bf(lg[nt][r]);
    }
    f32x4 oacc[4];
    #pragma unroll
    for (int ni = 0; ni < 4; ++ni) oacc[ni] = fzero;
    __builtin_amdgcn_s_setprio(1);
    #pragma unroll
    for (int ks = 0; ks < 9; ++ks) {
      s16x8 pf = *(const s16x8*)&Pl[wid][lr][ks*32 + lk];
      #pragma unroll
      for (int ni = 0; ni < 4; ++ni) {
        s16x8 vf = *(const s16x8*)&Vt[ni*16 + lr][ks*32 + lk];
        oacc[ni] = __builtin_amdgcn_mfma_f32_16x16x32_bf16(pf, vf, oacc[ni], 0, 0, 0);
      }
    }
    __builtin_amdgcn_s_setprio(0);
    #pragma unroll
    for (int ni = 0; ni < 4; ++ni)
      #pragma unroll
      for (int r = 0; r < 4; ++r) {
        int q = qt*16 + gg + r;
        if (q < S_ && q != 0) o[(size_t)(t*S_ + q)*D_ + h*64 + ni*16 + lr] = f2bf(oacc[ni][r] * is_[r]);
      }
  }
}

// ---------------------------------------------------------------- temporal attention
__global__ __launch_bounds__(256)
void attn_temporal_k(const short* __restrict__ qkv, short* __restrict__ o)
{
  __shared__ float Ql[4][16][68];
  __shared__ float Kl[4][16][68];
  __shared__ float Vl[4][16][68];
  __shared__ float Pl2[4][16][17];
  const int tid = threadIdx.x, lane = tid & 63, wid = tid >> 6;
  const int gw = blockIdx.x*4 + wid;
  const int s = gw >> 4, h = gw & 15;
  const int tt = lane >> 2, dp = (lane & 3) * 16;
  const short* base = qkv + (size_t)(tt*S_ + s)*3072 + h*64 + dp;
  #pragma unroll
  for (int part = 0; part < 3; ++part) {
    const short* bp = base + part*1024;
    s16x8 v0 = *(const s16x8*)(bp);
    s16x8 v1 = *(const s16x8*)(bp + 8);
    float* dst = (part == 0) ? &Ql[wid][tt][dp] : (part == 1) ? &Kl[wid][tt][dp] : &Vl[wid][tt][dp];
    #pragma unroll
    for (int j = 0; j < 8; ++j) { dst[j] = bf2f(v0[j]); dst[8 + j] = bf2f(v1[j]); }
  }
  __syncthreads();
  const int qr = lane >> 2;
  float qv[64];
  #pragma unroll
  for (int j = 0; j < 64; ++j) qv[j] = Ql[wid][qr][j];
  float pvals[4];
  #pragma unroll
  for (int i = 0; i < 4; ++i) {
    int kt = (lane & 3) + i*4;
    float d = 0.f;
    #pragma unroll
    for (int j = 0; j < 64; ++j) d += qv[j] * Kl[wid][kt][j];
    d *= 0.125f;
    bool keep = (kt <= qr) && (kt + 9 >= qr);
    pvals[i] = keep ? exp_softcap(d * 8.0f) : 0.f;   // exp_softcap takes raw logit (pre-0.125)
  }
  float sum = pvals[0] + pvals[1] + pvals[2] + pvals[3];
  sum += __shfl_xor(sum, 1);
  sum += __shfl_xor(sum, 2);
  float is = 1.f / sum;
  #pragma unroll
  for (int i = 0; i < 4; ++i) Pl2[wid][qr][(lane & 3) + i*4] = pvals[i] * is;
  __syncthreads();
  float acc[16];
  #pragma unroll
  for (int j = 0; j < 16; ++j) acc[j] = 0.f;
  #pragma unroll
  for (int kt = 0; kt < 16; ++kt) {
    float pv = Pl2[wid][qr][kt];
    #pragma unroll
    for (int j = 0; j < 16; ++j) acc[j] += pv * Vl[wid][kt][dp + j];
  }
  short* op = o + (size_t)(qr*S_ + s)*D_ + h*64 + dp;
  #pragma unroll
  for (int j = 0; j < 16; ++j) op[j] = f2bf(acc[j]);
}

// ---------------------------------------------------------------- conversions / prologue
struct CvtJobs {
  const float* src[10];
  short* dst[10];
  int end[10];
  int njobs;
};

__global__ void cvt_multi_k(CvtJobs jobs)
{
  int q = blockIdx.x*256 + threadIdx.x;
  int j = 0;
  while (j < jobs.njobs && q >= jobs.end[j]) ++j;
  if (j >= jobs.njobs) return;
  int base = (j == 0) ? 0 : jobs.end[j-1];
  size_t idx = (size_t)(q - base);
  float4 v = *(const float4*)(jobs.src[j] + idx*4);
  s16x4 ov; ov[0]=f2bf(v.x); ov[1]=f2bf(v.y); ov[2]=f2bf(v.z); ov[3]=f2bf(v.w);
  *(s16x4*)(jobs.dst[j] + idx*4) = ov;
}

__global__ void cvt_f32_bf16_k(const float* __restrict__ in, short* __restrict__ out, int n4)
{
  int i = blockIdx.x*256 + threadIdx.x;
  if (i >= n4) return;
  float4 v = *(const float4*)(in + (size_t)i*4);
  s16x4 ov; ov[0]=f2bf(v.x); ov[1]=f2bf(v.y); ov[2]=f2bf(v.z); ov[3]=f2bf(v.w);
  *(s16x4*)(out + (size_t)i*4) = ov;
}

// w12: permute rows so gate/val interleave in 16-blocks within 32 (fused swiglu epilogue)
__global__ void cvt_w12_k(const float* __restrict__ in, short* __restrict__ out)
{
  int pb = blockIdx.x;             // 8 layers * 8192 rows
  int l = pb >> 13, pr = pb & 8191;
  int c = pr >> 5, q = pr & 31;
  int orig = (q < 16) ? c*16 + q : DH_ + c*16 + (q - 16);
  const float* ip = in + ((size_t)l*8192 + orig)*1024 + threadIdx.x*4;
  short* op = out + ((size_t)l*8192 + pr)*1024 + threadIdx.x*4;
  float4 v = *(const float4*)ip;
  s16x4 ov; ov[0]=f2bf(v.x); ov[1]=f2bf(v.y); ov[2]=f2bf(v.z); ov[3]=f2bf(v.w);
  *(s16x4*)op = ov;
}

__global__ void timestep_embed_k(const float* __restrict__ sig, float* __restrict__ emb)
{
  int tid = threadIdx.x;
  int n = tid >> 4;
  int j0 = (tid & 15) * 16;
  float tv = sig[n];
  for (int j = j0; j < j0 + 16; ++j) {
    int half = j & 127;
    float freq = expf(-9.210340371976184f * (float)half / 128.f);
    float a = tv * freq;
    emb[n*256 + j] = (j < 128) ? cosf(a) : sinf(a);
  }
}

__global__ void noise_mlp1_k(const float* __restrict__ emb, const float* __restrict__ w1,
                             const float* __restrict__ b1, float* __restrict__ hid)
{
  const int o = blockIdx.x*256 + threadIdx.x;
  const int n = o >> 10, e = o & 1023;
  const float4* er = (const float4*)(emb + n*256);
  const float4* wr = (const float4*)(w1 + (size_t)e*256);
  float s = b1[e];
  for (int k = 0; k < 64; ++k) { float4 a = er[k]; float4 b = wr[k]; s += a.x*b.x + a.y*b.y + a.z*b.z + a.w*b.w; }
  hid[o] = s / (1.f + __expf(-s));
}

__global__ void noise_mlp2_k(const float* __restrict__ hid, const float* __restrict__ w2,
                             const float* __restrict__ b2, float* __restrict__ sg)
{
  const int o = blockIdx.x*256 + threadIdx.x;
  const int n = o >> 10, e = o & 1023;
  const float4* hr = (const float4*)(hid + n*1024);
  const float4* wr = (const float4*)(w2 + (size_t)e*1024);
  float s = b2[e];
  for (int k = 0; k < 256; ++k) { float4 a = hr[k]; float4 b = wr[k]; s += a.x*b.x + a.y*b.y + a.z*b.z + a.w*b.w; }
  sg[o] = s;
}

__global__ void act_embed_k(const float* __restrict__ actions, const float* __restrict__ base,
                            const float* __restrict__ apw, const float* __restrict__ apb,
                            float* __restrict__ ar)
{
  const int o = blockIdx.x*256 + threadIdx.x;
  const int n = o >> 10, e = o & 1023;
  float s = base[e] + apb[e];
  #pragma unroll
  for (int j = 0; j < 8; ++j) s += actions[n*8 + j] * apw[(size_t)e*8 + j];
  ar[o] = s;
}

__global__ void fill6_k(const float* __restrict__ sig, const float* __restrict__ act,
                        const float* __restrict__ reg, float* __restrict__ x)
{
  const int b = blockIdx.x;            // 16*6
  const int t = b / 6, s = b % 6;
  const int d = threadIdx.x * 4;
  float4 v;
  if (s == 0)      v = *(const float4*)(sig + t*D_ + d);
  else if (s == 1) v = *(const float4*)(act + t*D_ + d);
  else             v = *(const float4*)(reg + (s-2)*D_ + d);
  *(float4*)(x + (size_t)(t*S_ + s)*D_ + d) = v;
}

// ---------------------------------------------------------------- host
extern "C" void kernel_launch(void* const* d_in, const int* in_sizes, int n_in,
                              void* d_out, int out_size, void* d_ws, size_t ws_size,
                              hipStream_t stream)
{
  (void)in_sizes; (void)n_in; (void)out_size;
  const float* noisy   = (const float*)d_in[0];
  const float* sig_lv  = (const float*)d_in[1];
  const float* actions = (const float*)d_in[2];
  const float* in_proj = (const float*)d_in[3];
  const float* nw1     = (const float*)d_in[4];
  const float* nb1     = (const float*)d_in[5];
  const float* nw2     = (const float*)d_in[6];
  const float* nb2     = (const float*)d_in[7];
  const float* base_ae = (const float*)d_in[8];
  const float* apw     = (const float*)d_in[9];
  const float* apb     = (const float*)d_in[10];
  const float* regtok  = (const float*)d_in[11];
  const float* ln1w    = (const float*)d_in[12];
  const float* s_wqkv  = (const float*)d_in[13];
  const float* s_wo    = (const float*)d_in[14];
  const float* s_qg    = (const float*)d_in[15];
  const float* s_kg    = (const float*)d_in[16];
  const float* lntw    = (const float*)d_in[17];
  const float* t_wqkv  = (const float*)d_in[18];
  const float* t_wo    = (const float*)d_in[19];
  const float* t_qg    = (const float*)d_in[20];
  const float* t_kg    = (const float*)d_in[21];
  const float* ln2w    = (const float*)d_in[22];
  const float* w12     = (const float*)d_in[23];
  const float* w3      = (const float*)d_in[24];
  const float* fnw     = (const float*)d_in[25];
  const float* outw    = (const float*)d_in[26];
  const float* outb    = (const float*)d_in[27];

  char* p = (char*)d_ws;
  auto take = [&](size_t n) { char* r = p; p += n; return r; };
  float* x   = (float*)take((size_t)NTOK*D_*4);
  short* hb  = (short*)take((size_t)NTOK*D_*2);
  short* qkv = (short*)take((size_t)NTOK*3072*2);
  short* ob  = (short*)take((size_t)NTOK*D_*2);
  short* mb  = qkv;                               // spans qkv+ob exactly (NTOK*4096*2)
  short* nlb = (short*)take((size_t)4096*INDIM_*2);
  float* emb = (float*)take(16*256*4);
  float* hid = (float*)take(16*1024*4);
  float* sgb = (float*)take(16*1024*4);
  float* acr = (float*)take(16*1024*4);
  float* csS = (float*)take(S_*32*4);
  float* snS = (float*)take(S_*32*4);
  float* csT = (float*)take(16*32*4);
  float* snT = (float*)take(16*32*4);
  short* wqkv_s_bf = (short*)take((size_t)8*3*D_*D_*2);
  short* wo_s_bf   = (short*)take((size_t)8*D_*D_*2);
  short* wqkv_t_bf = (short*)take((size_t)2*3*D_*D_*2);
  short* wo_t_bf   = (short*)take((size_t)2*D_*D_*2);
  short* w12_bf    = (short*)take((size_t)8*2*DH_*D_*2);
  short* w3_bf     = (short*)take((size_t)8*D_*DH_*2);
  short* inp_bf    = (short*)take((size_t)D_*INDIM_*2);
  short* outw_bf   = (short*)take((size_t)INDIM_*D_*2);
  const size_t full_need = (size_t)(p - (char*)d_ws);
  const bool wb = ws_size >= full_need;

  if (wb) {
    CvtJobs jobs;
    int acc_q = 0, nj = 0;
    auto add = [&](const float* s, short* d, size_t elems) {
      jobs.src[nj] = s; jobs.dst[nj] = d;
      acc_q += (int)(elems / 4); jobs.end[nj] = acc_q; ++nj;
    };
    add(s_wqkv, wqkv_s_bf, (size_t)8*3*D_*D_);
    add(s_wo,   wo_s_bf,   (size_t)8*D_*D_);
    add(t_wqkv,                     wqkv_t_bf,                   (size_t)3*D_*D_);
    add(t_wqkv + (size_t)4*3*D_*D_, wqkv_t_bf + (size_t)3*D_*D_, (size_t)3*D_*D_);
    add(t_wo,                       wo_t_bf,                     (size_t)D_*D_);
    add(t_wo + (size_t)4*D_*D_,     wo_t_bf + (size_t)D_*D_,     (size_t)D_*D_);
    add(w3,   w3_bf,   (size_t)8*D_*DH_);
    add(in_proj, inp_bf, (size_t)D_*INDIM_);
    add(outw,    outw_bf,(size_t)INDIM_*D_);
    add(noisy,   nlb,    (size_t)4096*INDIM_);
    jobs.njobs = nj;
    cvt_multi_k<<<(acc_q + 255)/256, 256, 0, stream>>>(jobs);
    cvt_w12_k<<<65536, 256, 0, stream>>>(w12, w12_bf);
  } else {
    cvt_f32_bf16_k<<<3072, 256, 0, stream>>>(noisy, nlb, 4096*INDIM_/4);
  }
  rope_tab_k<<<33, 256, 0, stream>>>(csS, snS, S_);
  rope_tab_k<<<2,  256, 0, stream>>>(csT, snT, 16);

  // prologue
  timestep_embed_k<<<1, 256, 0, stream>>>(sig_lv, emb);
  noise_mlp1_k<<<64, 256, 0, stream>>>(emb, nw1, nb1, hid);
  noise_mlp2_k<<<64, 256, 0, stream>>>(hid, nw2, nb2, sgb);
  act_embed_k<<<64, 256, 0, stream>>>(actions, base_ae, apw, apb, acr);
  if (wb) gemm2<1,0,0,0,1,0,0,1><<<dim3(16,64), 256, 0, stream>>>(nlb, inp_bf,  nullptr, x, 4096, D_, INDIM_, nullptr, nullptr, nullptr, nullptr);
  else    gemm2<1,0,0,0,0,0,0,1><<<dim3(16,64), 256, 0, stream>>>(nlb, in_proj, nullptr, x, 4096, D_, INDIM_, nullptr, nullptr, nullptr, nullptr);
  fill6_k<<<96, 256, 0, stream>>>(sgb, acr, regtok, x);

  for (int l = 0; l < 8; ++l) {
    rmsnorm_k<0><<<NTOK/4, 256, 0, stream>>>(x, ln1w + l*D_, hb);
    if (wb) gemm2<0,0,0,1,1,0,1,0><<<dim3(24,33), 256, 0, stream>>>(hb, wqkv_s_bf + (size_t)l*3*D_*D_, nullptr, qkv, NTOK, 3*D_, D_, s_qg + l*HD_, s_kg + l*HD_, csS, snS);
    else    gemm2<0,0,0,1,0,0,1,0><<<dim3(24,33), 256, 0, stream>>>(hb, s_wqkv   + (size_t)l*3*D_*D_, nullptr, qkv, NTOK, 3*D_, D_, s_qg + l*HD_, s_kg + l*HD_, csS, snS);
    attn_spatial_k<<<256, 256, 0, stream>>>(qkv, ob);
    if (wb) gemm2<1,1,0,0,1,0,0,0><<<dim3(16,66), 256, 0, stream>>>(ob, wo_s_bf + (size_t)l*D_*D_, nullptr, x, NTOK, D_, D_, nullptr, nullptr, nullptr, nullptr);
    else    gemm2<1,1,0,0,0,0,0,0><<<dim3(16,66), 256, 0, stream>>>(ob, s_wo    + (size_t)l*D_*D_, nullptr, x, NTOK, D_, D_, nullptr, nullptr, nullptr, nullptr);
    if (l % 4 == 0) {
      const int ls = l / 4;
      rmsnorm_k<0><<<NTOK/4, 256, 0, stream>>>(x, lntw + l*D_, hb);
      if (wb) gemm2<0,0,0,1,1,0,2,0><<<dim3(24,33), 256, 0, stream>>>(hb, wqkv_t_bf + (size_t)ls*3*D_*D_, nullptr, qkv, NTOK, 3*D_, D_, t_qg + l*HD_, t_kg + l*HD_, csT, snT);
      else    gemm2<0,0,0,1,0,0,2,0><<<dim3(24,33), 256, 0, stream>>>(hb, t_wqkv    + (size_t)l*3*D_*D_,  nullptr, qkv, NTOK, 3*D_, D_, t_qg + l*HD_, t_kg + l*HD_, csT, snT);
      attn_temporal_k<<<1048, 256, 0, stream>>>(qkv, ob);
      if (wb) gemm2<1,1,0,0,1,0,0,0><<<dim3(16,66), 256, 0, stream>>>(ob, wo_t_bf + (size_t)ls*D_*D_, nullptr, x, NTOK, D_, D_, nullptr, nullptr, nullptr, nullptr);
      else    gemm2<1,1,0,0,0,0,0,0><<<dim3(16,66), 256, 0, stream>>>(ob, t_wo    + (size_t)l*D_*D_,  nullptr, x, NTOK, D_, D_, nullptr, nullptr, nullptr, nullptr);
    }
    rmsnorm_k<0><<<NTOK/4, 256, 0, stream>>>(x, ln2w + l*D_, hb);
    if (wb) gemm2<0,0,0,2,1,0,0,0><<<dim3(64,33), 256, 0, stream>>>(hb, w12_bf + (size_t)l*2*DH_*D_, nullptr, mb, NTOK, 2*DH_, D_, nullptr, nullptr, nullptr, nullptr);
    else    gemm2<0,0,0,2,0,1,0,0><<<dim3(64,33), 256, 0, stream>>>(hb, w12    + (size_t)l*2*DH_*D_, nullptr, mb, NTOK, 2*DH_, D_, nullptr, nullptr, nullptr, nullptr);
    if (wb) gemm2<1,1,0,0,1,0,0,0><<<dim3(16,66), 256, 0, stream>>>(mb, w3_bf + (size_t)l*D_*DH_, nullptr, x, NTOK, D_, DH_, nullptr, nullptr, nullptr, nullptr);
    else    gemm2<1,1,0,0,0,0,0,0><<<dim3(16,66), 256, 0, stream>>>(mb, w3    + (size_t)l*D_*DH_, nullptr, x, NTOK, D_, DH_, nullptr, nullptr, nullptr, nullptr);
  }
  rmsnorm_k<1><<<1024, 256, 0, stream>>>(x, fnw, hb);
  if (wb) gemm2<1,0,1,0,1,0,0,0><<<dim3(12,64), 256, 0, stream>>>(hb, outw_bf, outb, (float*)d_out, 4096, INDIM_, D_, nullptr, nullptr, nullptr, nullptr);
  else    gemm2<1,0,1,0,0,0,0,0><<<dim3(12,64), 256, 0, stream>>>(hb, outw,    outb, (float*)d_out, 4096, INDIM_, D_, nullptr, nullptr, nullptr, nullptr);
}